// Round 1
// baseline (468.474 us; speedup 1.0000x reference)
//
#include <hip/hip_runtime.h>

// BayesianMambaBlock on MI355X (gfx950).
// Pipeline: LN -> (xp,gate) GEMMs -> conv+silu -> S GEMM -> u -> ABCdt -> chunked scan -> gate*y -> out GEMM.
// GEMMs: bf16 MFMA 16x16x32, 128x128 tile, global_load_lds staging (m97 structure).

typedef unsigned short u16;
using short8 = __attribute__((ext_vector_type(8))) short;
using f32x4  = __attribute__((ext_vector_type(4))) float;

#define BATCH 2
#define SEQ   2048
#define DM    768
#define DI    1536
#define NST   16
#define LCH   64
#define NCH   32
#define NTOK  (BATCH*SEQ)   // 4096

__device__ __forceinline__ u16 f2b(float x) {
  unsigned u = __float_as_uint(x);
  u += 0x7FFFu + ((u >> 16) & 1u);   // round-to-nearest-even bf16
  return (u16)(u >> 16);
}
__device__ __forceinline__ float sigmoidf_(float x) { return 1.f / (1.f + expf(-x)); }
__device__ __forceinline__ float siluf_(float x) { return x / (1.f + expf(-x)); }

// ---------------- f32 -> bf16 cast (vectorized) ----------------
__global__ __launch_bounds__(256) void cast_bf16(const float* __restrict__ in, u16* __restrict__ out, int n4) {
  int i = blockIdx.x * 256 + threadIdx.x;
  if (i >= n4) return;
  float4 v = ((const float4*)in)[i];
  ushort4 o; o.x = f2b(v.x); o.y = f2b(v.y); o.z = f2b(v.z); o.w = f2b(v.w);
  ((ushort4*)out)[i] = o;
}

// ---------------- LayerNorm -> bf16 ----------------
__global__ __launch_bounds__(256) void ln_kernel(const float* __restrict__ x, const float* __restrict__ g,
                                                 const float* __restrict__ bb, u16* __restrict__ xn) {
  int m = blockIdx.x, tid = threadIdx.x;
  const float* xr = x + (size_t)m * DM;
  float v0 = xr[tid], v1 = xr[tid + 256], v2 = xr[tid + 512];
  float s  = v0 + v1 + v2;
  float s2 = fmaf(v0, v0, fmaf(v1, v1, v2 * v2));
  #pragma unroll
  for (int off = 32; off > 0; off >>= 1) { s += __shfl_down(s, off); s2 += __shfl_down(s2, off); }
  __shared__ float sh[8];
  int wave = tid >> 6, lane = tid & 63;
  if (lane == 0) { sh[wave] = s; sh[4 + wave] = s2; }
  __syncthreads();
  float S1 = sh[0] + sh[1] + sh[2] + sh[3];
  float S2 = sh[4] + sh[5] + sh[6] + sh[7];
  float mu = S1 * (1.f / DM);
  float var = S2 * (1.f / DM) - mu * mu;
  float rs = rsqrtf(var + 1e-5f);
  u16* o = xn + (size_t)m * DM;
  o[tid]       = f2b((v0 - mu) * rs * g[tid]       + bb[tid]);
  o[tid + 256] = f2b((v1 - mu) * rs * g[tid + 256] + bb[tid + 256]);
  o[tid + 512] = f2b((v2 - mu) * rs * g[tid + 512] + bb[tid + 512]);
}

// ---------------- bf16 MFMA NT-GEMM: C[M][N] = A[M][K] * B[N][K]^T + bias (+resid) ----------------
__device__ __forceinline__ void gll16(const void* g, void* l) {
  __builtin_amdgcn_global_load_lds((const __attribute__((address_space(1))) void*)g,
                                   (__attribute__((address_space(3))) void*)l, 16, 0, 0);
}

__global__ __launch_bounds__(256) void gemm_bt(const u16* __restrict__ A, const u16* __restrict__ B,
                                               const float* __restrict__ bias, const float* __restrict__ resid,
                                               float* __restrict__ C, int M, int N, int K) {
  __shared__ __align__(16) u16 As[128 * 32];
  __shared__ __align__(16) u16 Bs[128 * 32];
  const int tid = threadIdx.x, wave = tid >> 6, lane = tid & 63;
  const int m0 = blockIdx.y * 128, n0 = blockIdx.x * 128;
  const int wm = (wave >> 1) * 64, wn = (wave & 1) * 64;
  const int fr = lane & 15, fq = lane >> 4;
  f32x4 acc[4][4] = {};

  const int c0 = tid, c1 = tid + 256;   // 16B chunks: row=c>>2, koff=(c&3)*8
  const u16* Ag0 = A + (size_t)(m0 + (c0 >> 2)) * K + (c0 & 3) * 8;
  const u16* Ag1 = A + (size_t)(m0 + (c1 >> 2)) * K + (c1 & 3) * 8;
  const u16* Bg0 = B + (size_t)(n0 + (c0 >> 2)) * K + (c0 & 3) * 8;
  const u16* Bg1 = B + (size_t)(n0 + (c1 >> 2)) * K + (c1 & 3) * 8;
  u16* lA0 = As + (wave * 64) * 8;          // wave-uniform LDS base; HW adds lane*16B
  u16* lA1 = As + (256 + wave * 64) * 8;
  u16* lB0 = Bs + (wave * 64) * 8;
  u16* lB1 = Bs + (256 + wave * 64) * 8;

  for (int k0 = 0; k0 < K; k0 += 32) {
    gll16(Ag0 + k0, lA0);
    gll16(Ag1 + k0, lA1);
    gll16(Bg0 + k0, lB0);
    gll16(Bg1 + k0, lB1);
    __syncthreads();   // drains vmcnt before barrier
    short8 av[4], bv[4];
    #pragma unroll
    for (int i = 0; i < 4; ++i) av[i] = *(const short8*)(As + (wm + i * 16 + fr) * 32 + fq * 8);
    #pragma unroll
    for (int i = 0; i < 4; ++i) bv[i] = *(const short8*)(Bs + (wn + i * 16 + fr) * 32 + fq * 8);
    #pragma unroll
    for (int mi = 0; mi < 4; ++mi)
      #pragma unroll
      for (int ni = 0; ni < 4; ++ni)
        acc[mi][ni] = __builtin_amdgcn_mfma_f32_16x16x32_bf16(av[mi], bv[ni], acc[mi][ni], 0, 0, 0);
    __syncthreads();
  }

  #pragma unroll
  for (int ni = 0; ni < 4; ++ni) {
    int col = n0 + wn + ni * 16 + fr;
    float bv_ = bias[col];
    #pragma unroll
    for (int mi = 0; mi < 4; ++mi) {
      int row = m0 + wm + mi * 16 + fq * 4;
      #pragma unroll
      for (int j = 0; j < 4; ++j) {
        size_t off = (size_t)(row + j) * N + col;
        float v = acc[mi][ni][j] + bv_;
        if (resid) v += resid[off];
        C[off] = v;
      }
    }
  }
}

// ---------------- depthwise causal conv (k=4) + bias + silu ----------------
__global__ __launch_bounds__(256) void conv_silu(const float* __restrict__ xp, const float* __restrict__ cw,
                                                 const float* __restrict__ cb, float* __restrict__ xa,
                                                 u16* __restrict__ xab) {
  int idx = blockIdx.x * 256 + threadIdx.x;   // < NTOK*DI
  int d = idx % DI;
  int t = (idx / DI) % SEQ;
  float4 w = ((const float4*)cw)[d];          // conv_w[d][0][0..3]
  float acc = cb[d];
  if (t >= 3) acc = fmaf(xp[idx - 3 * DI], w.x, acc);
  if (t >= 2) acc = fmaf(xp[idx - 2 * DI], w.y, acc);
  if (t >= 1) acc = fmaf(xp[idx - 1 * DI], w.z, acc);
  acc = fmaf(xp[idx], w.w, acc);
  float s = siluf_(acc);
  xa[idx] = s;
  xab[idx] = f2b(s);
}

// ---------------- u = xa * sigmoid(Sp) ----------------
__global__ __launch_bounds__(256) void u_mul(const float* __restrict__ xa, const float* __restrict__ sp,
                                             float* __restrict__ u, int n4) {
  int i = blockIdx.x * 256 + threadIdx.x;
  if (i >= n4) return;
  float4 a = ((const float4*)xa)[i];
  float4 s = ((const float4*)sp)[i];
  float4 o;
  o.x = a.x * sigmoidf_(s.x); o.y = a.y * sigmoidf_(s.y);
  o.z = a.z * sigmoidf_(s.z); o.w = a.w * sigmoidf_(s.w);
  ((float4*)u)[i] = o;
}

// ---------------- A/dt/B/C projections (N=64 skinny) + decay ----------------
// 4 tokens per block, 1 wave per token; lanes 0-15:zA 16-31:zdt 32-47:B 48-63:C
__global__ __launch_bounds__(256) void abcd_kernel(const float* __restrict__ u,
    const float* __restrict__ WA, const float* __restrict__ Wdt,
    const float* __restrict__ WB, const float* __restrict__ WC,
    const float* __restrict__ bA, const float* __restrict__ bdt,
    const float* __restrict__ bB, const float* __restrict__ bC,
    float* __restrict__ dec, float* __restrict__ Bm, float* __restrict__ Cm) {
  __shared__ __align__(16) float ur[4 * DI];
  int tid = threadIdx.x, wave = tid >> 6, lane = tid & 63;
  int m0 = blockIdx.x * 4;
  const float4* usrc = (const float4*)(u + (size_t)m0 * DI);
  float4* udst = (float4*)ur;
  #pragma unroll
  for (int i = 0; i < 6; ++i) udst[tid + i * 256] = usrc[tid + i * 256];
  __syncthreads();
  int m = m0 + wave;
  int r = lane & 15;
  const float* Wrow; float bias;
  if (lane < 16)      { Wrow = WA  + (size_t)r * DI; bias = bA[r]; }
  else if (lane < 32) { Wrow = Wdt + (size_t)r * DI; bias = bdt[r]; }
  else if (lane < 48) { Wrow = WB  + (size_t)r * DI; bias = bB[r]; }
  else                { Wrow = WC  + (size_t)r * DI; bias = bC[r]; }
  const float4* W4 = (const float4*)Wrow;
  const float4* u4 = (const float4*)(ur + wave * DI);
  float acc = 0.f;
  for (int i = 0; i < DI / 4; ++i) {
    float4 w = W4[i], uu = u4[i];
    acc = fmaf(w.x, uu.x, acc); acc = fmaf(w.y, uu.y, acc);
    acc = fmaf(w.z, uu.z, acc); acc = fmaf(w.w, uu.w, acc);
  }
  float v = acc + bias;
  float vdt = __shfl(v, r + 16, 64);          // zdt partner for lanes 0-15
  size_t o = (size_t)m * NST + r;
  if (lane < 16)                    dec[o] = expf(-expf(v + vdt));  // exp(A*dt)=exp(-exp(zA+zdt))
  else if (lane >= 32 && lane < 48) Bm[o] = v;
  else if (lane >= 48)              Cm[o] = v;
}

// ---------------- chunked selective scan ----------------
// phase1: per-chunk local scan from h=0 -> lend[c][b][d][16]; P[c][b][16]=prod(dec)
__global__ __launch_bounds__(256) void scan_phase1(const float* __restrict__ u, const float* __restrict__ dec,
                                                   const float* __restrict__ Bm, float* __restrict__ lend,
                                                   float* __restrict__ P) {
  __shared__ float dl[LCH * NST], bl[LCH * NST];
  int bid = blockIdx.x;
  int dblk = bid % 6, b = (bid / 6) % BATCH, c = bid / (6 * BATCH);
  int d = dblk * 256 + threadIdx.x;
  int t0 = c * LCH;
  size_t base16 = (size_t)(b * SEQ + t0) * NST;
  for (int i = threadIdx.x; i < LCH * NST; i += 256) { dl[i] = dec[base16 + i]; bl[i] = Bm[base16 + i]; }
  __syncthreads();
  float h[NST];
  #pragma unroll
  for (int n = 0; n < NST; ++n) h[n] = 0.f;
  const float* up = u + (size_t)(b * SEQ + t0) * DI + d;
  for (int t = 0; t < LCH; ++t) {
    float uu = up[(size_t)t * DI];
    #pragma unroll
    for (int n = 0; n < NST; ++n) h[n] = fmaf(h[n], dl[t * NST + n], bl[t * NST + n] * uu);
  }
  float* lo = lend + ((size_t)(c * BATCH + b) * DI + d) * NST;
  ((float4*)lo)[0] = make_float4(h[0], h[1], h[2], h[3]);
  ((float4*)lo)[1] = make_float4(h[4], h[5], h[6], h[7]);
  ((float4*)lo)[2] = make_float4(h[8], h[9], h[10], h[11]);
  ((float4*)lo)[3] = make_float4(h[12], h[13], h[14], h[15]);
  if (dblk == 0 && threadIdx.x < NST) {
    float pr = 1.f;
    for (int t = 0; t < LCH; ++t) pr *= dl[t * NST + threadIdx.x];
    P[(size_t)(c * BATCH + b) * NST + threadIdx.x] = pr;
  }
}

// phase2: cross-chunk scan; Hin[c] = state entering chunk c
__global__ __launch_bounds__(256) void scan_phase2(const float* __restrict__ lend, const float* __restrict__ P,
                                                   float* __restrict__ Hin) {
  int flat = blockIdx.x * 256 + threadIdx.x;  // < BATCH*DI
  int d = flat % DI, b = flat / DI;
  float h[NST];
  #pragma unroll
  for (int n = 0; n < NST; ++n) h[n] = 0.f;
  for (int c = 0; c < NCH; ++c) {
    size_t idx = ((size_t)(c * BATCH + b) * DI + d) * NST;
    float4* hp = (float4*)(Hin + idx);
    hp[0] = make_float4(h[0], h[1], h[2], h[3]);
    hp[1] = make_float4(h[4], h[5], h[6], h[7]);
    hp[2] = make_float4(h[8], h[9], h[10], h[11]);
    hp[3] = make_float4(h[12], h[13], h[14], h[15]);
    const float4* le = (const float4*)(lend + idx);
    const float* pc = P + (size_t)(c * BATCH + b) * NST;
    float4 l0 = le[0], l1 = le[1], l2 = le[2], l3 = le[3];
    h[0] = fmaf(pc[0],  h[0],  l0.x); h[1] = fmaf(pc[1],  h[1],  l0.y);
    h[2] = fmaf(pc[2],  h[2],  l0.z); h[3] = fmaf(pc[3],  h[3],  l0.w);
    h[4] = fmaf(pc[4],  h[4],  l1.x); h[5] = fmaf(pc[5],  h[5],  l1.y);
    h[6] = fmaf(pc[6],  h[6],  l1.z); h[7] = fmaf(pc[7],  h[7],  l1.w);
    h[8] = fmaf(pc[8],  h[8],  l2.x); h[9] = fmaf(pc[9],  h[9],  l2.y);
    h[10] = fmaf(pc[10], h[10], l2.z); h[11] = fmaf(pc[11], h[11], l2.w);
    h[12] = fmaf(pc[12], h[12], l3.x); h[13] = fmaf(pc[13], h[13], l3.y);
    h[14] = fmaf(pc[14], h[14], l3.z); h[15] = fmaf(pc[15], h[15], l3.w);
  }
}

// phase3: replay chunk from Hin, emit y
__global__ __launch_bounds__(256) void scan_phase3(const float* __restrict__ u, const float* __restrict__ dec,
                                                   const float* __restrict__ Bm, const float* __restrict__ Cm,
                                                   const float* __restrict__ Hin, float* __restrict__ y) {
  __shared__ float dl[LCH * NST], bl[LCH * NST], cl[LCH * NST];
  int bid = blockIdx.x;
  int dblk = bid % 6, b = (bid / 6) % BATCH, c = bid / (6 * BATCH);
  int d = dblk * 256 + threadIdx.x;
  int t0 = c * LCH;
  size_t base16 = (size_t)(b * SEQ + t0) * NST;
  for (int i = threadIdx.x; i < LCH * NST; i += 256) {
    dl[i] = dec[base16 + i]; bl[i] = Bm[base16 + i]; cl[i] = Cm[base16 + i];
  }
  __syncthreads();
  float h[NST];
  const float4* hi = (const float4*)(Hin + ((size_t)(c * BATCH + b) * DI + d) * NST);
  float4 h0 = hi[0], h1 = hi[1], h2 = hi[2], h3 = hi[3];
  h[0]=h0.x; h[1]=h0.y; h[2]=h0.z; h[3]=h0.w; h[4]=h1.x; h[5]=h1.y; h[6]=h1.z; h[7]=h1.w;
  h[8]=h2.x; h[9]=h2.y; h[10]=h2.z; h[11]=h2.w; h[12]=h3.x; h[13]=h3.y; h[14]=h3.z; h[15]=h3.w;
  const float* up = u + (size_t)(b * SEQ + t0) * DI + d;
  float* yp = y + (size_t)(b * SEQ + t0) * DI + d;
  for (int t = 0; t < LCH; ++t) {
    float uu = up[(size_t)t * DI];
    float acc = 0.f;
    #pragma unroll
    for (int n = 0; n < NST; ++n) {
      h[n] = fmaf(h[n], dl[t * NST + n], bl[t * NST + n] * uu);
      acc = fmaf(h[n], cl[t * NST + n], acc);
    }
    yp[(size_t)t * DI] = acc;
  }
}

// ---------------- gy = silu(gatep) * y -> bf16 ----------------
__global__ __launch_bounds__(256) void gatemul(const float* __restrict__ gp, const float* __restrict__ y,
                                               u16* __restrict__ gy, int n4) {
  int i = blockIdx.x * 256 + threadIdx.x;
  if (i >= n4) return;
  float4 g = ((const float4*)gp)[i];
  float4 v = ((const float4*)y)[i];
  ushort4 o;
  o.x = f2b(siluf_(g.x) * v.x); o.y = f2b(siluf_(g.y) * v.y);
  o.z = f2b(siluf_(g.z) * v.z); o.w = f2b(siluf_(g.w) * v.w);
  ((ushort4*)gy)[i] = o;
}

extern "C" void kernel_launch(void* const* d_in, const int* in_sizes, int n_in,
                              void* d_out, int out_size, void* d_ws, size_t ws_size,
                              hipStream_t stream) {
  const float* x      = (const float*)d_in[0];
  const float* ln_g   = (const float*)d_in[1];
  const float* ln_b   = (const float*)d_in[2];
  const float* W_in   = (const float*)d_in[3];
  const float* b_in   = (const float*)d_in[4];
  const float* conv_w = (const float*)d_in[5];
  const float* conv_b = (const float*)d_in[6];
  const float* W_A    = (const float*)d_in[7];
  const float* b_A    = (const float*)d_in[8];
  const float* W_B    = (const float*)d_in[9];
  const float* b_B    = (const float*)d_in[10];
  const float* W_C    = (const float*)d_in[11];
  const float* b_C    = (const float*)d_in[12];
  const float* W_dt   = (const float*)d_in[13];
  const float* b_dt   = (const float*)d_in[14];
  const float* W_S    = (const float*)d_in[15];
  const float* b_S    = (const float*)d_in[16];
  const float* W_gate = (const float*)d_in[17];
  const float* b_gate = (const float*)d_in[18];
  const float* W_out  = (const float*)d_in[19];
  const float* b_out  = (const float*)d_in[20];
  float* out = (float*)d_out;

  // workspace carve-out (~145 MB incl. aliasing)
  char* p = (char*)d_ws;
  auto alloc = [&](size_t bytes) { char* r = p; p += (bytes + 255) & ~(size_t)255; return r; };
  u16*   Winb   = (u16*)alloc((size_t)DI * DM * 2);
  u16*   Wgateb = (u16*)alloc((size_t)DI * DM * 2);
  u16*   WSb    = (u16*)alloc((size_t)DI * DI * 2);     // first half of W_S only
  u16*   Woutb  = (u16*)alloc((size_t)DM * DI * 2);
  u16*   xnb    = (u16*)alloc((size_t)NTOK * DM * 2);
  float* xp     = (float*)alloc((size_t)NTOK * DI * 4); // later reused as Sp
  float* gatep  = (float*)alloc((size_t)NTOK * DI * 4);
  float* xa     = (float*)alloc((size_t)NTOK * DI * 4); // later reused as y
  u16*   xab    = (u16*)alloc((size_t)NTOK * DI * 2);   // later reused as gy
  float* u      = (float*)alloc((size_t)NTOK * DI * 4);
  float* decb   = (float*)alloc((size_t)NTOK * NST * 4);
  float* Bmb    = (float*)alloc((size_t)NTOK * NST * 4);
  float* Cmb    = (float*)alloc((size_t)NTOK * NST * 4);
  float* lend   = (float*)alloc((size_t)NCH * BATCH * DI * NST * 4);
  float* Hin    = (float*)alloc((size_t)NCH * BATCH * DI * NST * 4);
  float* P      = (float*)alloc((size_t)NCH * BATCH * NST * 4);
  float* Sp = xp;
  float* y  = xa;
  u16*   gy = xab;

  // weight casts
  cast_bf16<<<(DI * DM / 4 + 255) / 256, 256, 0, stream>>>(W_in, Winb, DI * DM / 4);
  cast_bf16<<<(DI * DM / 4 + 255) / 256, 256, 0, stream>>>(W_gate, Wgateb, DI * DM / 4);
  cast_bf16<<<(DI * DI / 4 + 255) / 256, 256, 0, stream>>>(W_S, WSb, DI * DI / 4);
  cast_bf16<<<(DM * DI / 4 + 255) / 256, 256, 0, stream>>>(W_out, Woutb, DM * DI / 4);

  ln_kernel<<<NTOK, 256, 0, stream>>>(x, ln_g, ln_b, xnb);

  gemm_bt<<<dim3(DI / 128, NTOK / 128), 256, 0, stream>>>(xnb, Winb, b_in, nullptr, xp, NTOK, DI, DM);
  gemm_bt<<<dim3(DI / 128, NTOK / 128), 256, 0, stream>>>(xnb, Wgateb, b_gate, nullptr, gatep, NTOK, DI, DM);

  conv_silu<<<NTOK * DI / 256, 256, 0, stream>>>(xp, conv_w, conv_b, xa, xab);

  gemm_bt<<<dim3(DI / 128, NTOK / 128), 256, 0, stream>>>(xab, WSb, b_S, nullptr, Sp, NTOK, DI, DI);

  u_mul<<<NTOK * DI / 4 / 256, 256, 0, stream>>>(xa, Sp, u, NTOK * DI / 4);

  abcd_kernel<<<NTOK / 4, 256, 0, stream>>>(u, W_A, W_dt, W_B, W_C, b_A, b_dt, b_B, b_C, decb, Bmb, Cmb);

  scan_phase1<<<NCH * BATCH * (DI / 256), 256, 0, stream>>>(u, decb, Bmb, lend, P);
  scan_phase2<<<BATCH * DI / 256, 256, 0, stream>>>(lend, P, Hin);
  scan_phase3<<<NCH * BATCH * (DI / 256), 256, 0, stream>>>(u, decb, Bmb, Cmb, Hin, y);

  gatemul<<<NTOK * DI / 4 / 256, 256, 0, stream>>>(gatep, y, gy, NTOK * DI / 4);

  gemm_bt<<<dim3(DM / 128, NTOK / 128), 256, 0, stream>>>(gy, Woutb, b_out, x, out, NTOK, DM, DI);
}

// Round 4
// 320.423 us; speedup vs baseline: 1.4621x; 1.4621x over previous
//
#include <hip/hip_runtime.h>

// BayesianMambaBlock on MI355X (gfx950).
// LN -> (xp,gate) GEMMs -> conv+silu -> S GEMM (fused u) -> abcd GEMM (fused dec/B/C) ->
// chunked scan (phase3 fused gate) -> out GEMM (+resid).

typedef unsigned short u16;
using short8 = __attribute__((ext_vector_type(8))) short;
using f32x4  = __attribute__((ext_vector_type(4))) float;

#define BATCH 2
#define SEQ   2048
#define DM    768
#define DI    1536
#define NST   16
#define LCH   64
#define NCH   32
#define NTOK  (BATCH*SEQ)   // 4096

__device__ __forceinline__ u16 f2b(float x) {
  unsigned u = __float_as_uint(x);
  u += 0x7FFFu + ((u >> 16) & 1u);   // round-to-nearest-even bf16
  return (u16)(u >> 16);
}
__device__ __forceinline__ float sigmoidf_(float x) { return 1.f / (1.f + expf(-x)); }
__device__ __forceinline__ float siluf_(float x) { return x / (1.f + expf(-x)); }

// ---------------- f32 -> bf16 cast (vectorized) ----------------
__global__ __launch_bounds__(256) void cast_bf16(const float* __restrict__ in, u16* __restrict__ out, int n4) {
  int i = blockIdx.x * 256 + threadIdx.x;
  if (i >= n4) return;
  float4 v = ((const float4*)in)[i];
  ushort4 o; o.x = f2b(v.x); o.y = f2b(v.y); o.z = f2b(v.z); o.w = f2b(v.w);
  ((ushort4*)out)[i] = o;
}

// ---------------- concat W_A/W_dt/W_B/W_C -> bf16 [64][DI] + bias64 ----------------
__global__ __launch_bounds__(256) void cast_wabcd(const float* __restrict__ WA, const float* __restrict__ Wdt,
                                                  const float* __restrict__ WB, const float* __restrict__ WC,
                                                  const float* __restrict__ bA, const float* __restrict__ bdt,
                                                  const float* __restrict__ bB, const float* __restrict__ bC,
                                                  u16* __restrict__ Wb, float* __restrict__ bias64) {
  int i = blockIdx.x * 256 + threadIdx.x;   // < 64*DI
  if (i >= 64 * DI) return;
  int r = i / DI, c = i % DI;
  const float* src = (r < 16) ? WA + (size_t)r * DI
                  : (r < 32) ? Wdt + (size_t)(r - 16) * DI
                  : (r < 48) ? WB + (size_t)(r - 32) * DI
                             : WC + (size_t)(r - 48) * DI;
  Wb[i] = f2b(src[c]);
  if (i < 64) bias64[i] = (i < 16) ? bA[i] : (i < 32) ? bdt[i - 16] : (i < 48) ? bB[i - 32] : bC[i - 48];
}

// ---------------- LayerNorm -> bf16 ----------------
__global__ __launch_bounds__(256) void ln_kernel(const float* __restrict__ x, const float* __restrict__ g,
                                                 const float* __restrict__ bb, u16* __restrict__ xn) {
  int m = blockIdx.x, tid = threadIdx.x;
  const float* xr = x + (size_t)m * DM;
  float v0 = xr[tid], v1 = xr[tid + 256], v2 = xr[tid + 512];
  float s  = v0 + v1 + v2;
  float s2 = fmaf(v0, v0, fmaf(v1, v1, v2 * v2));
  #pragma unroll
  for (int off = 32; off > 0; off >>= 1) { s += __shfl_down(s, off); s2 += __shfl_down(s2, off); }
  __shared__ float sh[8];
  int wave = tid >> 6, lane = tid & 63;
  if (lane == 0) { sh[wave] = s; sh[4 + wave] = s2; }
  __syncthreads();
  float S1 = sh[0] + sh[1] + sh[2] + sh[3];
  float S2 = sh[4] + sh[5] + sh[6] + sh[7];
  float mu = S1 * (1.f / DM);
  float var = S2 * (1.f / DM) - mu * mu;
  float rs = rsqrtf(var + 1e-5f);
  u16* o = xn + (size_t)m * DM;
  o[tid]       = f2b((v0 - mu) * rs * g[tid]       + bb[tid]);
  o[tid + 256] = f2b((v1 - mu) * rs * g[tid + 256] + bb[tid + 256]);
  o[tid + 512] = f2b((v2 - mu) * rs * g[tid + 512] + bb[tid + 512]);
}

// ---------------- bf16 MFMA NT-GEMM: out = A[M][K] * B[N][K]^T + bias ----------------
// MODE 0: C f32 = acc + bias (+aux residual)
// MODE 1: u-mode: uf = aux * sigmoid(acc+bias); write uf (f32) + ub (bf16)
__device__ __forceinline__ void gll16(const void* g, void* l) {
  __builtin_amdgcn_global_load_lds((const __attribute__((address_space(1))) void*)g,
                                   (__attribute__((address_space(3))) void*)l, 16, 0, 0);
}

template <int MODE>
__global__ __launch_bounds__(256) void gemm_bt(const u16* __restrict__ A, const u16* __restrict__ B,
                                               const float* __restrict__ bias, const float* __restrict__ aux,
                                               float* __restrict__ C, u16* __restrict__ Cb,
                                               int M, int N, int K) {
  __shared__ __align__(16) u16 As[128 * 32];
  __shared__ __align__(16) u16 Bs[128 * 32];
  const int tid = threadIdx.x, wave = tid >> 6, lane = tid & 63;
  const int m0 = blockIdx.y * 128, n0 = blockIdx.x * 128;
  const int wm = (wave >> 1) * 64, wn = (wave & 1) * 64;
  const int fr = lane & 15, fq = lane >> 4;
  f32x4 acc[4][4] = {};

  const int c0 = tid, c1 = tid + 256;   // 16B chunks: row=c>>2, koff=(c&3)*8
  const u16* Ag0 = A + (size_t)(m0 + (c0 >> 2)) * K + (c0 & 3) * 8;
  const u16* Ag1 = A + (size_t)(m0 + (c1 >> 2)) * K + (c1 & 3) * 8;
  const u16* Bg0 = B + (size_t)(n0 + (c0 >> 2)) * K + (c0 & 3) * 8;
  const u16* Bg1 = B + (size_t)(n0 + (c1 >> 2)) * K + (c1 & 3) * 8;
  u16* lA0 = As + (wave * 64) * 8;          // wave-uniform LDS base; HW adds lane*16B
  u16* lA1 = As + (256 + wave * 64) * 8;
  u16* lB0 = Bs + (wave * 64) * 8;
  u16* lB1 = Bs + (256 + wave * 64) * 8;

  for (int k0 = 0; k0 < K; k0 += 32) {
    gll16(Ag0 + k0, lA0);
    gll16(Ag1 + k0, lA1);
    gll16(Bg0 + k0, lB0);
    gll16(Bg1 + k0, lB1);
    __syncthreads();
    short8 av[4], bv[4];
    #pragma unroll
    for (int i = 0; i < 4; ++i) av[i] = *(const short8*)(As + (wm + i * 16 + fr) * 32 + fq * 8);
    #pragma unroll
    for (int i = 0; i < 4; ++i) bv[i] = *(const short8*)(Bs + (wn + i * 16 + fr) * 32 + fq * 8);
    #pragma unroll
    for (int mi = 0; mi < 4; ++mi)
      #pragma unroll
      for (int ni = 0; ni < 4; ++ni)
        acc[mi][ni] = __builtin_amdgcn_mfma_f32_16x16x32_bf16(av[mi], bv[ni], acc[mi][ni], 0, 0, 0);
    __syncthreads();
  }

  #pragma unroll
  for (int ni = 0; ni < 4; ++ni) {
    int col = n0 + wn + ni * 16 + fr;
    float bv_ = bias[col];
    #pragma unroll
    for (int mi = 0; mi < 4; ++mi) {
      int row = m0 + wm + mi * 16 + fq * 4;
      #pragma unroll
      for (int j = 0; j < 4; ++j) {
        size_t off = (size_t)(row + j) * N + col;
        float z = acc[mi][ni][j] + bv_;
        if (MODE == 0) {
          if (aux) z += aux[off];
          C[off] = z;
        } else {
          float uv = aux[off] * sigmoidf_(z);
          C[off] = uv;
          Cb[off] = f2b(uv);
        }
      }
    }
  }
}

// ---------------- abcd GEMM: Z = ub[M][K] * Wabcd[64][K]^T; fused dec/Bm/Cm epilogue ----------------
__global__ __launch_bounds__(256) void gemm_abcd(const u16* __restrict__ A, const u16* __restrict__ B,
                                                 const float* __restrict__ bias64,
                                                 float* __restrict__ dec, float* __restrict__ Bm,
                                                 float* __restrict__ Cm, int M, int K) {
  __shared__ __align__(16) u16 As[64 * 32];
  __shared__ __align__(16) u16 Bs[64 * 32];
  const int tid = threadIdx.x, wave = tid >> 6, lane = tid & 63;
  const int m0 = blockIdx.x * 64;
  const int wm = wave * 16;
  const int fr = lane & 15, fq = lane >> 4;
  f32x4 acc[4] = {};

  const int c0 = tid;   // 256 chunks of 16B cover 64x32
  const u16* Ag0 = A + (size_t)(m0 + (c0 >> 2)) * K + (c0 & 3) * 8;
  const u16* Bg0 = B + (size_t)(c0 >> 2) * K + (c0 & 3) * 8;
  u16* lA0 = As + (wave * 64) * 8;
  u16* lB0 = Bs + (wave * 64) * 8;

  for (int k0 = 0; k0 < K; k0 += 32) {
    gll16(Ag0 + k0, lA0);
    gll16(Bg0 + k0, lB0);
    __syncthreads();
    short8 av = *(const short8*)(As + (wm + fr) * 32 + fq * 8);
    short8 bv[4];
    #pragma unroll
    for (int i = 0; i < 4; ++i) bv[i] = *(const short8*)(Bs + (i * 16 + fr) * 32 + fq * 8);
    #pragma unroll
    for (int ni = 0; ni < 4; ++ni)
      acc[ni] = __builtin_amdgcn_mfma_f32_16x16x32_bf16(av, bv[ni], acc[ni], 0, 0, 0);
    __syncthreads();
  }

  // cols: ni=0 -> zA[fr], ni=1 -> zdt[fr], ni=2 -> B[fr], ni=3 -> C[fr]; same lane holds all four.
  float bA_ = bias64[fr], bDt_ = bias64[16 + fr], bB_ = bias64[32 + fr], bC_ = bias64[48 + fr];
  #pragma unroll
  for (int j = 0; j < 4; ++j) {
    int row = m0 + wm + fq * 4 + j;
    size_t o = (size_t)row * NST + fr;
    float zA = acc[0][j] + bA_, zDt = acc[1][j] + bDt_;
    dec[o] = expf(-expf(zA + zDt));
    Bm[o]  = acc[2][j] + bB_;
    Cm[o]  = acc[3][j] + bC_;
  }
}

// ---------------- depthwise causal conv (k=4) + bias + silu ----------------
__global__ __launch_bounds__(256) void conv_silu(const float* __restrict__ xp, const float* __restrict__ cw,
                                                 const float* __restrict__ cb, float* __restrict__ xa,
                                                 u16* __restrict__ xab) {
  int idx = blockIdx.x * 256 + threadIdx.x;   // < NTOK*DI
  int d = idx % DI;
  int t = (idx / DI) % SEQ;
  float4 w = ((const float4*)cw)[d];          // conv_w[d][0][0..3]
  float acc = cb[d];
  if (t >= 3) acc = fmaf(xp[idx - 3 * DI], w.x, acc);
  if (t >= 2) acc = fmaf(xp[idx - 2 * DI], w.y, acc);
  if (t >= 1) acc = fmaf(xp[idx - 1 * DI], w.z, acc);
  acc = fmaf(xp[idx], w.w, acc);
  float s = siluf_(acc);
  xa[idx] = s;
  xab[idx] = f2b(s);
}

// ---------------- chunked selective scan ----------------
// phase1: per-chunk local scan from h=0 -> lend[c][b][d][16]; P[c][b][16]=prod(dec)
__global__ __launch_bounds__(256) void scan_phase1(const float* __restrict__ u, const float* __restrict__ dec,
                                                   const float* __restrict__ Bm, float* __restrict__ lend,
                                                   float* __restrict__ P) {
  __shared__ float dl[LCH * NST], bl[LCH * NST];
  int bid = blockIdx.x;
  int dblk = bid % 6, b = (bid / 6) % BATCH, c = bid / (6 * BATCH);
  int d = dblk * 256 + threadIdx.x;
  int t0 = c * LCH;
  size_t base16 = (size_t)(b * SEQ + t0) * NST;
  for (int i = threadIdx.x; i < LCH * NST; i += 256) { dl[i] = dec[base16 + i]; bl[i] = Bm[base16 + i]; }
  __syncthreads();
  float h[NST];
  #pragma unroll
  for (int n = 0; n < NST; ++n) h[n] = 0.f;
  const float* up = u + (size_t)(b * SEQ + t0) * DI + d;
  for (int t = 0; t < LCH; ++t) {
    float uu = up[(size_t)t * DI];
    #pragma unroll
    for (int n = 0; n < NST; ++n) h[n] = fmaf(h[n], dl[t * NST + n], bl[t * NST + n] * uu);
  }
  float* lo = lend + ((size_t)(c * BATCH + b) * DI + d) * NST;
  ((float4*)lo)[0] = make_float4(h[0], h[1], h[2], h[3]);
  ((float4*)lo)[1] = make_float4(h[4], h[5], h[6], h[7]);
  ((float4*)lo)[2] = make_float4(h[8], h[9], h[10], h[11]);
  ((float4*)lo)[3] = make_float4(h[12], h[13], h[14], h[15]);
  if (dblk == 0 && threadIdx.x < NST) {
    float pr = 1.f;
    for (int t = 0; t < LCH; ++t) pr *= dl[t * NST + threadIdx.x];
    P[(size_t)(c * BATCH + b) * NST + threadIdx.x] = pr;
  }
}

// phase2: cross-chunk scan; Hin[c] = state entering chunk c
__global__ __launch_bounds__(256) void scan_phase2(const float* __restrict__ lend, const float* __restrict__ P,
                                                   float* __restrict__ Hin) {
  int flat = blockIdx.x * 256 + threadIdx.x;  // < BATCH*DI
  int d = flat % DI, b = flat / DI;
  float h[NST];
  #pragma unroll
  for (int n = 0; n < NST; ++n) h[n] = 0.f;
  for (int c = 0; c < NCH; ++c) {
    size_t idx = ((size_t)(c * BATCH + b) * DI + d) * NST;
    float4* hp = (float4*)(Hin + idx);
    hp[0] = make_float4(h[0], h[1], h[2], h[3]);
    hp[1] = make_float4(h[4], h[5], h[6], h[7]);
    hp[2] = make_float4(h[8], h[9], h[10], h[11]);
    hp[3] = make_float4(h[12], h[13], h[14], h[15]);
    const float4* le = (const float4*)(lend + idx);
    const float* pc = P + (size_t)(c * BATCH + b) * NST;
    float4 l0 = le[0], l1 = le[1], l2 = le[2], l3 = le[3];
    h[0] = fmaf(pc[0],  h[0],  l0.x); h[1] = fmaf(pc[1],  h[1],  l0.y);
    h[2] = fmaf(pc[2],  h[2],  l0.z); h[3] = fmaf(pc[3],  h[3],  l0.w);
    h[4] = fmaf(pc[4],  h[4],  l1.x); h[5] = fmaf(pc[5],  h[5],  l1.y);
    h[6] = fmaf(pc[6],  h[6],  l1.z); h[7] = fmaf(pc[7],  h[7],  l1.w);
    h[8] = fmaf(pc[8],  h[8],  l2.x); h[9] = fmaf(pc[9],  h[9],  l2.y);
    h[10] = fmaf(pc[10], h[10], l2.z); h[11] = fmaf(pc[11], h[11], l2.w);
    h[12] = fmaf(pc[12], h[12], l3.x); h[13] = fmaf(pc[13], h[13], l3.y);
    h[14] = fmaf(pc[14], h[14], l3.z); h[15] = fmaf(pc[15], h[15], l3.w);
  }
}

// phase3: replay chunk from Hin, emit gy = bf16(silu(gatep) * y)
__global__ __launch_bounds__(256) void scan_phase3(const float* __restrict__ u, const float* __restrict__ dec,
                                                   const float* __restrict__ Bm, const float* __restrict__ Cm,
                                                   const float* __restrict__ Hin, const float* __restrict__ gatep,
                                                   u16* __restrict__ gy) {
  __shared__ float dl[LCH * NST], bl[LCH * NST], cl[LCH * NST];
  int bid = blockIdx.x;
  int dblk = bid % 6, b = (bid / 6) % BATCH, c = bid / (6 * BATCH);
  int d = dblk * 256 + threadIdx.x;
  int t0 = c * LCH;
  size_t base16 = (size_t)(b * SEQ + t0) * NST;
  for (int i = threadIdx.x; i < LCH * NST; i += 256) {
    dl[i] = dec[base16 + i]; bl[i] = Bm[base16 + i]; cl[i] = Cm[base16 + i];
  }
  __syncthreads();
  float h[NST];
  const float4* hi = (const float4*)(Hin + ((size_t)(c * BATCH + b) * DI + d) * NST);
  float4 h0 = hi[0], h1 = hi[1], h2 = hi[2], h3 = hi[3];
  h[0]=h0.x; h[1]=h0.y; h[2]=h0.z; h[3]=h0.w; h[4]=h1.x; h[5]=h1.y; h[6]=h1.z; h[7]=h1.w;
  h[8]=h2.x; h[9]=h2.y; h[10]=h2.z; h[11]=h2.w; h[12]=h3.x; h[13]=h3.y; h[14]=h3.z; h[15]=h3.w;
  const float* up = u + (size_t)(b * SEQ + t0) * DI + d;
  const float* gp = gatep + (size_t)(b * SEQ + t0) * DI + d;
  u16* yp = gy + (size_t)(b * SEQ + t0) * DI + d;
  for (int t = 0; t < LCH; ++t) {
    float uu = up[(size_t)t * DI];
    float acc = 0.f;
    #pragma unroll
    for (int n = 0; n < NST; ++n) {
      h[n] = fmaf(h[n], dl[t * NST + n], bl[t * NST + n] * uu);
      acc = fmaf(h[n], cl[t * NST + n], acc);
    }
    float g = gp[(size_t)t * DI];
    yp[(size_t)t * DI] = f2b(siluf_(g) * acc);
  }
}

extern "C" void kernel_launch(void* const* d_in, const int* in_sizes, int n_in,
                              void* d_out, int out_size, void* d_ws, size_t ws_size,
                              hipStream_t stream) {
  const float* x      = (const float*)d_in[0];
  const float* ln_g   = (const float*)d_in[1];
  const float* ln_b   = (const float*)d_in[2];
  const float* W_in   = (const float*)d_in[3];
  const float* b_in   = (const float*)d_in[4];
  const float* conv_w = (const float*)d_in[5];
  const float* conv_b = (const float*)d_in[6];
  const float* W_A    = (const float*)d_in[7];
  const float* b_A    = (const float*)d_in[8];
  const float* W_B    = (const float*)d_in[9];
  const float* b_B    = (const float*)d_in[10];
  const float* W_C    = (const float*)d_in[11];
  const float* b_C    = (const float*)d_in[12];
  const float* W_dt   = (const float*)d_in[13];
  const float* b_dt   = (const float*)d_in[14];
  const float* W_S    = (const float*)d_in[15];
  const float* b_S    = (const float*)d_in[16];
  const float* W_gate = (const float*)d_in[17];
  const float* b_gate = (const float*)d_in[18];
  const float* W_out  = (const float*)d_in[19];
  const float* b_out  = (const float*)d_in[20];
  float* out = (float*)d_out;

  char* p = (char*)d_ws;
  auto alloc = [&](size_t bytes) { char* r = p; p += (bytes + 255) & ~(size_t)255; return r; };
  u16*   Winb   = (u16*)alloc((size_t)DI * DM * 2);
  u16*   Wgateb = (u16*)alloc((size_t)DI * DM * 2);
  u16*   WSb    = (u16*)alloc((size_t)DI * DI * 2);     // first half of W_S only
  u16*   Woutb  = (u16*)alloc((size_t)DM * DI * 2);
  u16*   Wabcd  = (u16*)alloc((size_t)64 * DI * 2);
  float* bias64 = (float*)alloc(64 * 4);
  u16*   xnb    = (u16*)alloc((size_t)NTOK * DM * 2);
  float* xp     = (float*)alloc((size_t)NTOK * DI * 4);
  float* gatep  = (float*)alloc((size_t)NTOK * DI * 4);
  float* xa     = (float*)alloc((size_t)NTOK * DI * 4);
  u16*   xab    = (u16*)alloc((size_t)NTOK * DI * 2);   // reused as gy after S GEMM
  float* u      = (float*)alloc((size_t)NTOK * DI * 4);
  u16*   ub     = (u16*)alloc((size_t)NTOK * DI * 2);
  float* decb   = (float*)alloc((size_t)NTOK * NST * 4);
  float* Bmb    = (float*)alloc((size_t)NTOK * NST * 4);
  float* Cmb    = (float*)alloc((size_t)NTOK * NST * 4);
  float* lend   = (float*)alloc((size_t)NCH * BATCH * DI * NST * 4);
  float* Hin    = (float*)alloc((size_t)NCH * BATCH * DI * NST * 4);
  float* P      = (float*)alloc((size_t)NCH * BATCH * NST * 4);
  u16* gy = xab;

  // weight casts
  cast_bf16<<<(DI * DM / 4 + 255) / 256, 256, 0, stream>>>(W_in, Winb, DI * DM / 4);
  cast_bf16<<<(DI * DM / 4 + 255) / 256, 256, 0, stream>>>(W_gate, Wgateb, DI * DM / 4);
  cast_bf16<<<(DI * DI / 4 + 255) / 256, 256, 0, stream>>>(W_S, WSb, DI * DI / 4);
  cast_bf16<<<(DM * DI / 4 + 255) / 256, 256, 0, stream>>>(W_out, Woutb, DM * DI / 4);
  cast_wabcd<<<(64 * DI + 255) / 256, 256, 0, stream>>>(W_A, W_dt, W_B, W_C, b_A, b_dt, b_B, b_C, Wabcd, bias64);

  ln_kernel<<<NTOK, 256, 0, stream>>>(x, ln_g, ln_b, xnb);

  gemm_bt<0><<<dim3(DI / 128, NTOK / 128), 256, 0, stream>>>(xnb, Winb, b_in, nullptr, xp, nullptr, NTOK, DI, DM);
  gemm_bt<0><<<dim3(DI / 128, NTOK / 128), 256, 0, stream>>>(xnb, Wgateb, b_gate, nullptr, gatep, nullptr, NTOK, DI, DM);

  conv_silu<<<NTOK * DI / 256, 256, 0, stream>>>(xp, conv_w, conv_b, xa, xab);

  // S GEMM with fused u = xa * sigmoid(Sp): writes u (f32) + ub (bf16)
  gemm_bt<1><<<dim3(DI / 128, NTOK / 128), 256, 0, stream>>>(xab, WSb, b_S, xa, u, ub, NTOK, DI, DI);

  gemm_abcd<<<NTOK / 64, 256, 0, stream>>>(ub, Wabcd, bias64, decb, Bmb, Cmb, NTOK, DI);

  scan_phase1<<<NCH * BATCH * (DI / 256), 256, 0, stream>>>(u, decb, Bmb, lend, P);
  scan_phase2<<<BATCH * DI / 256, 256, 0, stream>>>(lend, P, Hin);
  scan_phase3<<<NCH * BATCH * (DI / 256), 256, 0, stream>>>(u, decb, Bmb, Cmb, Hin, gatep, gy);

  gemm_bt<0><<<dim3(DM / 128, NTOK / 128), 256, 0, stream>>>(gy, Woutb, b_out, x, out, nullptr, NTOK, DM, DI);
}

// Round 5
// 283.190 us; speedup vs baseline: 1.6543x; 1.1315x over previous
//
#include <hip/hip_runtime.h>

// BayesianMambaBlock on MI355X (gfx950).
// LN -> fused (in|gate) GEMM (bf16 out) -> conv+silu (bf16) -> S GEMM (fused u, bf16 out) ->
// abcd GEMM (fused dec/B/C) -> chunked scan (phase3 fused gate) -> out GEMM (+resid, f32).
// GEMM LDS uses chunk-XOR swizzle: pre-swizzled global source + swizzled ds_read (linear LDS dest).

typedef unsigned short u16;
using short8 = __attribute__((ext_vector_type(8))) short;
using f32x4  = __attribute__((ext_vector_type(4))) float;

#define BATCH 2
#define SEQ   2048
#define DM    768
#define DI    1536
#define NIG   (2*DI)        // fused in+gate width 3072
#define NST   16
#define LCH   64
#define NCH   32
#define NTOK  (BATCH*SEQ)   // 4096

__device__ __forceinline__ u16 f2b(float x) {
  unsigned u = __float_as_uint(x);
  u += 0x7FFFu + ((u >> 16) & 1u);   // round-to-nearest-even bf16
  return (u16)(u >> 16);
}
__device__ __forceinline__ float b2f(u16 v) { return __uint_as_float((unsigned)v << 16); }
__device__ __forceinline__ float sigmoidf_(float x) { return 1.f / (1.f + expf(-x)); }
__device__ __forceinline__ float siluf_(float x) { return x / (1.f + expf(-x)); }

// ---------------- f32 -> bf16 cast (vectorized) ----------------
__global__ __launch_bounds__(256) void cast_bf16(const float* __restrict__ in, u16* __restrict__ out, int n4) {
  int i = blockIdx.x * 256 + threadIdx.x;
  if (i >= n4) return;
  float4 v = ((const float4*)in)[i];
  ushort4 o; o.x = f2b(v.x); o.y = f2b(v.y); o.z = f2b(v.z); o.w = f2b(v.w);
  ((ushort4*)out)[i] = o;
}

// ---------------- concat W_in|W_gate -> bf16 [3072][768] + bias3072 ----------------
__global__ __launch_bounds__(256) void cast_ingate(const float* __restrict__ Wi, const float* __restrict__ Wg,
                                                   const float* __restrict__ bi, const float* __restrict__ bg,
                                                   u16* __restrict__ Wb, float* __restrict__ bias) {
  int i = blockIdx.x * 256 + threadIdx.x;   // < NIG*DM
  if (i >= NIG * DM) return;
  int r = i / DM, c = i % DM;
  Wb[i] = f2b(r < DI ? Wi[(size_t)r * DM + c] : Wg[(size_t)(r - DI) * DM + c]);
  if (i < NIG) bias[i] = (i < DI) ? bi[i] : bg[i - DI];
}

// ---------------- concat W_A/W_dt/W_B/W_C -> bf16 [64][DI] + bias64 ----------------
__global__ __launch_bounds__(256) void cast_wabcd(const float* __restrict__ WA, const float* __restrict__ Wdt,
                                                  const float* __restrict__ WB, const float* __restrict__ WC,
                                                  const float* __restrict__ bA, const float* __restrict__ bdt,
                                                  const float* __restrict__ bB, const float* __restrict__ bC,
                                                  u16* __restrict__ Wb, float* __restrict__ bias64) {
  int i = blockIdx.x * 256 + threadIdx.x;   // < 64*DI
  if (i >= 64 * DI) return;
  int r = i / DI, c = i % DI;
  const float* src = (r < 16) ? WA + (size_t)r * DI
                  : (r < 32) ? Wdt + (size_t)(r - 16) * DI
                  : (r < 48) ? WB + (size_t)(r - 32) * DI
                             : WC + (size_t)(r - 48) * DI;
  Wb[i] = f2b(src[c]);
  if (i < 64) bias64[i] = (i < 16) ? bA[i] : (i < 32) ? bdt[i - 16] : (i < 48) ? bB[i - 32] : bC[i - 48];
}

// ---------------- LayerNorm -> bf16 ----------------
__global__ __launch_bounds__(256) void ln_kernel(const float* __restrict__ x, const float* __restrict__ g,
                                                 const float* __restrict__ bb, u16* __restrict__ xn) {
  int m = blockIdx.x, tid = threadIdx.x;
  const float* xr = x + (size_t)m * DM;
  float v0 = xr[tid], v1 = xr[tid + 256], v2 = xr[tid + 512];
  float s  = v0 + v1 + v2;
  float s2 = fmaf(v0, v0, fmaf(v1, v1, v2 * v2));
  #pragma unroll
  for (int off = 32; off > 0; off >>= 1) { s += __shfl_down(s, off); s2 += __shfl_down(s2, off); }
  __shared__ float sh[8];
  int wave = tid >> 6, lane = tid & 63;
  if (lane == 0) { sh[wave] = s; sh[4 + wave] = s2; }
  __syncthreads();
  float S1 = sh[0] + sh[1] + sh[2] + sh[3];
  float S2 = sh[4] + sh[5] + sh[6] + sh[7];
  float mu = S1 * (1.f / DM);
  float var = S2 * (1.f / DM) - mu * mu;
  float rs = rsqrtf(var + 1e-5f);
  u16* o = xn + (size_t)m * DM;
  o[tid]       = f2b((v0 - mu) * rs * g[tid]       + bb[tid]);
  o[tid + 256] = f2b((v1 - mu) * rs * g[tid + 256] + bb[tid + 256]);
  o[tid + 512] = f2b((v2 - mu) * rs * g[tid + 512] + bb[tid + 512]);
}

// ---------------- bf16 MFMA NT-GEMM: acc = A[M][K] * B[N][K]^T + bias ----------------
// MODE 0: C f32 = acc + bias + aux(resid, f32)
// MODE 1: u-mode: uv = b2f(auxb) * sigmoid(acc+bias); Cb = bf16(uv)
// MODE 2: Cb = bf16(acc + bias)
__device__ __forceinline__ void gll16(const void* g, void* l) {
  __builtin_amdgcn_global_load_lds((const __attribute__((address_space(1))) void*)g,
                                   (__attribute__((address_space(3))) void*)l, 16, 0, 0);
}

template <int MODE>
__global__ __launch_bounds__(256) void gemm_bt(const u16* __restrict__ A, const u16* __restrict__ B,
                                               const float* __restrict__ bias, const float* __restrict__ aux,
                                               const u16* __restrict__ auxb,
                                               float* __restrict__ C, u16* __restrict__ Cb,
                                               int M, int N, int K) {
  __shared__ __align__(16) u16 As[128 * 32];
  __shared__ __align__(16) u16 Bs[128 * 32];
  const int tid = threadIdx.x, wave = tid >> 6, lane = tid & 63;
  const int m0 = blockIdx.y * 128, n0 = blockIdx.x * 128;
  const int wm = (wave >> 1) * 64, wn = (wave & 1) * 64;
  const int fr = lane & 15, fq = lane >> 4;
  f32x4 acc[4][4] = {};

  // staging: LDS chunk c (linear dest) holds global k-chunk (c&3)^((c>>3)&3) of row c>>2
  const int c0 = tid, c1 = tid + 256;
  const u16* Ag0 = A + (size_t)(m0 + (c0 >> 2)) * K + ((c0 & 3) ^ ((c0 >> 3) & 3)) * 8;
  const u16* Ag1 = A + (size_t)(m0 + (c1 >> 2)) * K + ((c1 & 3) ^ ((c1 >> 3) & 3)) * 8;
  const u16* Bg0 = B + (size_t)(n0 + (c0 >> 2)) * K + ((c0 & 3) ^ ((c0 >> 3) & 3)) * 8;
  const u16* Bg1 = B + (size_t)(n0 + (c1 >> 2)) * K + ((c1 & 3) ^ ((c1 >> 3) & 3)) * 8;
  u16* lA0 = As + (wave * 64) * 8;          // wave-uniform LDS base; HW adds lane*16B
  u16* lA1 = As + (256 + wave * 64) * 8;
  u16* lB0 = Bs + (wave * 64) * 8;
  u16* lB1 = Bs + (256 + wave * 64) * 8;

  // swizzled ds_read offsets (u16 units), conflict-free (2-way) per 8 bank-slots
  int offA[4], offB[4];
  #pragma unroll
  for (int i = 0; i < 4; ++i) {
    int ra = wm + i * 16 + fr;
    int rb = wn + i * 16 + fr;
    offA[i] = ra * 32 + (fq ^ ((ra >> 1) & 3)) * 8;
    offB[i] = rb * 32 + (fq ^ ((rb >> 1) & 3)) * 8;
  }

  for (int k0 = 0; k0 < K; k0 += 32) {
    gll16(Ag0 + k0, lA0);
    gll16(Ag1 + k0, lA1);
    gll16(Bg0 + k0, lB0);
    gll16(Bg1 + k0, lB1);
    __syncthreads();
    short8 av[4], bv[4];
    #pragma unroll
    for (int i = 0; i < 4; ++i) av[i] = *(const short8*)(As + offA[i]);
    #pragma unroll
    for (int i = 0; i < 4; ++i) bv[i] = *(const short8*)(Bs + offB[i]);
    #pragma unroll
    for (int mi = 0; mi < 4; ++mi)
      #pragma unroll
      for (int ni = 0; ni < 4; ++ni)
        acc[mi][ni] = __builtin_amdgcn_mfma_f32_16x16x32_bf16(av[mi], bv[ni], acc[mi][ni], 0, 0, 0);
    __syncthreads();
  }

  #pragma unroll
  for (int ni = 0; ni < 4; ++ni) {
    int col = n0 + wn + ni * 16 + fr;
    float bv_ = bias[col];
    #pragma unroll
    for (int mi = 0; mi < 4; ++mi) {
      int row = m0 + wm + mi * 16 + fq * 4;
      #pragma unroll
      for (int j = 0; j < 4; ++j) {
        size_t off = (size_t)(row + j) * N + col;
        float z = acc[mi][ni][j] + bv_;
        if (MODE == 0) {
          C[off] = z + aux[off];
        } else if (MODE == 1) {
          Cb[off] = f2b(b2f(auxb[off]) * sigmoidf_(z));
        } else {
          Cb[off] = f2b(z);
        }
      }
    }
  }
}

// ---------------- abcd GEMM: Z = ub[M][K] * Wabcd[64][K]^T; fused dec/Bm/Cm epilogue ----------------
__global__ __launch_bounds__(256) void gemm_abcd(const u16* __restrict__ A, const u16* __restrict__ B,
                                                 const float* __restrict__ bias64,
                                                 float* __restrict__ dec, float* __restrict__ Bm,
                                                 float* __restrict__ Cm, int M, int K) {
  __shared__ __align__(16) u16 As[64 * 32];
  __shared__ __align__(16) u16 Bs[64 * 32];
  const int tid = threadIdx.x, wave = tid >> 6, lane = tid & 63;
  const int m0 = blockIdx.x * 64;
  const int wm = wave * 16;
  const int fr = lane & 15, fq = lane >> 4;
  f32x4 acc[4] = {};

  const int c0 = tid;   // 256 chunks of 16B cover 64x32
  const u16* Ag0 = A + (size_t)(m0 + (c0 >> 2)) * K + (c0 & 3) * 8;
  const u16* Bg0 = B + (size_t)(c0 >> 2) * K + (c0 & 3) * 8;
  u16* lA0 = As + (wave * 64) * 8;
  u16* lB0 = Bs + (wave * 64) * 8;

  for (int k0 = 0; k0 < K; k0 += 32) {
    gll16(Ag0 + k0, lA0);
    gll16(Bg0 + k0, lB0);
    __syncthreads();
    short8 av = *(const short8*)(As + (wm + fr) * 32 + fq * 8);
    short8 bv[4];
    #pragma unroll
    for (int i = 0; i < 4; ++i) bv[i] = *(const short8*)(Bs + (i * 16 + fr) * 32 + fq * 8);
    #pragma unroll
    for (int ni = 0; ni < 4; ++ni)
      acc[ni] = __builtin_amdgcn_mfma_f32_16x16x32_bf16(av, bv[ni], acc[ni], 0, 0, 0);
    __syncthreads();
  }

  // cols: ni=0 -> zA[fr], ni=1 -> zdt[fr], ni=2 -> B[fr], ni=3 -> C[fr]; same lane holds all four.
  float bA_ = bias64[fr], bDt_ = bias64[16 + fr], bB_ = bias64[32 + fr], bC_ = bias64[48 + fr];
  #pragma unroll
  for (int j = 0; j < 4; ++j) {
    int row = m0 + wm + fq * 4 + j;
    size_t o = (size_t)row * NST + fr;
    float zA = acc[0][j] + bA_, zDt = acc[1][j] + bDt_;
    dec[o] = expf(-expf(zA + zDt));
    Bm[o]  = acc[2][j] + bB_;
    Cm[o]  = acc[3][j] + bC_;
  }
}

// ---------------- depthwise causal conv (k=4) + bias + silu; reads bf16 xpg, writes bf16 ----------------
__global__ __launch_bounds__(256) void conv_silu(const u16* __restrict__ xpg, const float* __restrict__ cw,
                                                 const float* __restrict__ cb, u16* __restrict__ xab) {
  int idx = blockIdx.x * 256 + threadIdx.x;   // < NTOK*DI
  int d = idx % DI;
  int token = idx / DI;
  int t = token % SEQ;
  size_t base = (size_t)token * NIG + d;
  float4 w = ((const float4*)cw)[d];          // conv_w[d][0][0..3]
  float acc = cb[d];
  if (t >= 3) acc = fmaf(b2f(xpg[base - 3 * NIG]), w.x, acc);
  if (t >= 2) acc = fmaf(b2f(xpg[base - 2 * NIG]), w.y, acc);
  if (t >= 1) acc = fmaf(b2f(xpg[base - 1 * NIG]), w.z, acc);
  acc = fmaf(b2f(xpg[base]), w.w, acc);
  xab[idx] = f2b(siluf_(acc));
}

// ---------------- chunked selective scan ----------------
// phase1: per-chunk local scan from h=0 -> lend[c][b][d][16]; P[c][b][16]=prod(dec)
__global__ __launch_bounds__(256) void scan_phase1(const u16* __restrict__ ub, const float* __restrict__ dec,
                                                   const float* __restrict__ Bm, float* __restrict__ lend,
                                                   float* __restrict__ P) {
  __shared__ float dl[LCH * NST], bl[LCH * NST];
  int bid = blockIdx.x;
  int dblk = bid % 6, b = (bid / 6) % BATCH, c = bid / (6 * BATCH);
  int d = dblk * 256 + threadIdx.x;
  int t0 = c * LCH;
  size_t base16 = (size_t)(b * SEQ + t0) * NST;
  for (int i = threadIdx.x; i < LCH * NST; i += 256) { dl[i] = dec[base16 + i]; bl[i] = Bm[base16 + i]; }
  __syncthreads();
  float h[NST];
  #pragma unroll
  for (int n = 0; n < NST; ++n) h[n] = 0.f;
  const u16* up = ub + (size_t)(b * SEQ + t0) * DI + d;
  for (int t = 0; t < LCH; ++t) {
    float uu = b2f(up[(size_t)t * DI]);
    #pragma unroll
    for (int n = 0; n < NST; ++n) h[n] = fmaf(h[n], dl[t * NST + n], bl[t * NST + n] * uu);
  }
  float* lo = lend + ((size_t)(c * BATCH + b) * DI + d) * NST;
  ((float4*)lo)[0] = make_float4(h[0], h[1], h[2], h[3]);
  ((float4*)lo)[1] = make_float4(h[4], h[5], h[6], h[7]);
  ((float4*)lo)[2] = make_float4(h[8], h[9], h[10], h[11]);
  ((float4*)lo)[3] = make_float4(h[12], h[13], h[14], h[15]);
  if (dblk == 0 && threadIdx.x < NST) {
    float pr = 1.f;
    for (int t = 0; t < LCH; ++t) pr *= dl[t * NST + threadIdx.x];
    P[(size_t)(c * BATCH + b) * NST + threadIdx.x] = pr;
  }
}

// phase2: cross-chunk scan; Hin[c] = state entering chunk c
__global__ __launch_bounds__(256) void scan_phase2(const float* __restrict__ lend, const float* __restrict__ P,
                                                   float* __restrict__ Hin) {
  int flat = blockIdx.x * 256 + threadIdx.x;  // < BATCH*DI
  int d = flat % DI, b = flat / DI;
  float h[NST];
  #pragma unroll
  for (int n = 0; n < NST; ++n) h[n] = 0.f;
  for (int c = 0; c < NCH; ++c) {
    size_t idx = ((size_t)(c * BATCH + b) * DI + d) * NST;
    float4* hp = (float4*)(Hin + idx);
    hp[0] = make_float4(h[0], h[1], h[2], h[3]);
    hp[1] = make_float4(h[4], h[5], h[6], h[7]);
    hp[2] = make_float4(h[8], h[9], h[10], h[11]);
    hp[3] = make_float4(h[12], h[13], h[14], h[15]);
    const float4* le = (const float4*)(lend + idx);
    const float* pc = P + (size_t)(c * BATCH + b) * NST;
    float4 l0 = le[0], l1 = le[1], l2 = le[2], l3 = le[3];
    h[0] = fmaf(pc[0],  h[0],  l0.x); h[1] = fmaf(pc[1],  h[1],  l0.y);
    h[2] = fmaf(pc[2],  h[2],  l0.z); h[3] = fmaf(pc[3],  h[3],  l0.w);
    h[4] = fmaf(pc[4],  h[4],  l1.x); h[5] = fmaf(pc[5],  h[5],  l1.y);
    h[6] = fmaf(pc[6],  h[6],  l1.z); h[7] = fmaf(pc[7],  h[7],  l1.w);
    h[8] = fmaf(pc[8],  h[8],  l2.x); h[9] = fmaf(pc[9],  h[9],  l2.y);
    h[10] = fmaf(pc[10], h[10], l2.z); h[11] = fmaf(pc[11], h[11], l2.w);
    h[12] = fmaf(pc[12], h[12], l3.x); h[13] = fmaf(pc[13], h[13], l3.y);
    h[14] = fmaf(pc[14], h[14], l3.z); h[15] = fmaf(pc[15], h[15], l3.w);
  }
}

// phase3: replay chunk from Hin, emit gy = bf16(silu(gate) * y); gate is cols DI..2DI of xpg
__global__ __launch_bounds__(256) void scan_phase3(const u16* __restrict__ ub, const float* __restrict__ dec,
                                                   const float* __restrict__ Bm, const float* __restrict__ Cm,
                                                   const float* __restrict__ Hin, const u16* __restrict__ xpg,
                                                   u16* __restrict__ gy) {
  __shared__ float dl[LCH * NST], bl[LCH * NST], cl[LCH * NST];
  int bid = blockIdx.x;
  int dblk = bid % 6, b = (bid / 6) % BATCH, c = bid / (6 * BATCH);
  int d = dblk * 256 + threadIdx.x;
  int t0 = c * LCH;
  size_t base16 = (size_t)(b * SEQ + t0) * NST;
  for (int i = threadIdx.x; i < LCH * NST; i += 256) {
    dl[i] = dec[base16 + i]; bl[i] = Bm[base16 + i]; cl[i] = Cm[base16 + i];
  }
  __syncthreads();
  float h[NST];
  const float4* hi = (const float4*)(Hin + ((size_t)(c * BATCH + b) * DI + d) * NST);
  float4 h0 = hi[0], h1 = hi[1], h2 = hi[2], h3 = hi[3];
  h[0]=h0.x; h[1]=h0.y; h[2]=h0.z; h[3]=h0.w; h[4]=h1.x; h[5]=h1.y; h[6]=h1.z; h[7]=h1.w;
  h[8]=h2.x; h[9]=h2.y; h[10]=h2.z; h[11]=h2.w; h[12]=h3.x; h[13]=h3.y; h[14]=h3.z; h[15]=h3.w;
  const u16* up = ub + (size_t)(b * SEQ + t0) * DI + d;
  const u16* gp = xpg + (size_t)(b * SEQ + t0) * NIG + DI + d;
  u16* yp = gy + (size_t)(b * SEQ + t0) * DI + d;
  for (int t = 0; t < LCH; ++t) {
    float uu = b2f(up[(size_t)t * DI]);
    float acc = 0.f;
    #pragma unroll
    for (int n = 0; n < NST; ++n) {
      h[n] = fmaf(h[n], dl[t * NST + n], bl[t * NST + n] * uu);
      acc = fmaf(h[n], cl[t * NST + n], acc);
    }
    float g = b2f(gp[(size_t)t * NIG]);
    yp[(size_t)t * DI] = f2b(siluf_(g) * acc);
  }
}

extern "C" void kernel_launch(void* const* d_in, const int* in_sizes, int n_in,
                              void* d_out, int out_size, void* d_ws, size_t ws_size,
                              hipStream_t stream) {
  const float* x      = (const float*)d_in[0];
  const float* ln_g   = (const float*)d_in[1];
  const float* ln_b   = (const float*)d_in[2];
  const float* W_in   = (const float*)d_in[3];
  const float* b_in   = (const float*)d_in[4];
  const float* conv_w = (const float*)d_in[5];
  const float* conv_b = (const float*)d_in[6];
  const float* W_A    = (const float*)d_in[7];
  const float* b_A    = (const float*)d_in[8];
  const float* W_B    = (const float*)d_in[9];
  const float* b_B    = (const float*)d_in[10];
  const float* W_C    = (const float*)d_in[11];
  const float* b_C    = (const float*)d_in[12];
  const float* W_dt   = (const float*)d_in[13];
  const float* b_dt   = (const float*)d_in[14];
  const float* W_S    = (const float*)d_in[15];
  const float* b_S    = (const float*)d_in[16];
  const float* W_gate = (const float*)d_in[17];
  const float* b_gate = (const float*)d_in[18];
  const float* W_out  = (const float*)d_in[19];
  const float* b_out  = (const float*)d_in[20];
  float* out = (float*)d_out;

  char* p = (char*)d_ws;
  auto alloc = [&](size_t bytes) { char* r = p; p += (bytes + 255) & ~(size_t)255; return r; };
  u16*   Wigb    = (u16*)alloc((size_t)NIG * DM * 2);   // [3072][768] = W_in | W_gate
  float* biasig  = (float*)alloc((size_t)NIG * 4);
  u16*   WSb     = (u16*)alloc((size_t)DI * DI * 2);    // first half of W_S only
  u16*   Woutb   = (u16*)alloc((size_t)DM * DI * 2);
  u16*   Wabcd   = (u16*)alloc((size_t)64 * DI * 2);
  float* bias64  = (float*)alloc(64 * 4);
  u16*   xnb     = (u16*)alloc((size_t)NTOK * DM * 2);
  u16*   xpg     = (u16*)alloc((size_t)NTOK * NIG * 2); // [tok][3072]: xp | gate (bf16)
  u16*   xab     = (u16*)alloc((size_t)NTOK * DI * 2);  // silu(conv) bf16; reused as gy
  u16*   ub      = (u16*)alloc((size_t)NTOK * DI * 2);  // u bf16
  float* decb    = (float*)alloc((size_t)NTOK * NST * 4);
  float* Bmb     = (float*)alloc((size_t)NTOK * NST * 4);
  float* Cmb     = (float*)alloc((size_t)NTOK * NST * 4);
  float* lend    = (float*)alloc((size_t)NCH * BATCH * DI * NST * 4);
  float* Hin     = (float*)alloc((size_t)NCH * BATCH * DI * NST * 4);
  float* P       = (float*)alloc((size_t)NCH * BATCH * NST * 4);
  u16* gy = xab;

  // weight prep
  cast_ingate<<<(NIG * DM + 255) / 256, 256, 0, stream>>>(W_in, W_gate, b_in, b_gate, Wigb, biasig);
  cast_bf16<<<(DI * DI / 4 + 255) / 256, 256, 0, stream>>>(W_S, WSb, DI * DI / 4);
  cast_bf16<<<(DM * DI / 4 + 255) / 256, 256, 0, stream>>>(W_out, Woutb, DM * DI / 4);
  cast_wabcd<<<(64 * DI + 255) / 256, 256, 0, stream>>>(W_A, W_dt, W_B, W_C, b_A, b_dt, b_B, b_C, Wabcd, bias64);

  ln_kernel<<<NTOK, 256, 0, stream>>>(x, ln_g, ln_b, xnb);

  // fused in|gate GEMM -> xpg bf16
  gemm_bt<2><<<dim3(NIG / 128, NTOK / 128), 256, 0, stream>>>(xnb, Wigb, biasig, nullptr, nullptr,
                                                              nullptr, xpg, NTOK, NIG, DM);

  conv_silu<<<NTOK * DI / 256, 256, 0, stream>>>(xpg, conv_w, conv_b, xab);

  // S GEMM with fused u = xa * sigmoid(Sp) -> ub bf16 (aux = xab, same buffer as A operand)
  gemm_bt<1><<<dim3(DI / 128, NTOK / 128), 256, 0, stream>>>(xab, WSb, b_S, nullptr, xab,
                                                             nullptr, ub, NTOK, DI, DI);

  gemm_abcd<<<NTOK / 64, 256, 0, stream>>>(ub, Wabcd, bias64, decb, Bmb, Cmb, NTOK, DI);

  scan_phase1<<<NCH * BATCH * (DI / 256), 256, 0, stream>>>(ub, decb, Bmb, lend, P);
  scan_phase2<<<BATCH * DI / 256, 256, 0, stream>>>(lend, P, Hin);
  scan_phase3<<<NCH * BATCH * (DI / 256), 256, 0, stream>>>(ub, decb, Bmb, Cmb, Hin, xpg, gy);

  // out GEMM + residual (f32 out)
  gemm_bt<0><<<dim3(DM / 128, NTOK / 128), 256, 0, stream>>>(gy, Woutb, b_out, x, nullptr,
                                                             out, nullptr, NTOK, DM, DI);
}

// Round 6
// 258.501 us; speedup vs baseline: 1.8123x; 1.0955x over previous
//
#include <hip/hip_runtime.h>

// BayesianMambaBlock on MI355X (gfx950).
// LN -> fused (in|gate) GEMM (bf16 out) -> conv+silu (bf16) -> S GEMM (fused u, bf16 out) ->
// abcd GEMM (fused dec/B/C) -> chunked scan (phase3 fused gate) -> out GEMM (+resid, f32).
// gemm_bt: 512 threads / 8 waves (32x64 wave tile), chunk-XOR LDS swizzle, XCD-aware block swizzle.

typedef unsigned short u16;
using short8 = __attribute__((ext_vector_type(8))) short;
using f32x4  = __attribute__((ext_vector_type(4))) float;

#define BATCH 2
#define SEQ   2048
#define DM    768
#define DI    1536
#define NIG   (2*DI)        // fused in+gate width 3072
#define NST   16
#define LCH   64
#define NCH   32
#define NTOK  (BATCH*SEQ)   // 4096

__device__ __forceinline__ u16 f2b(float x) {
  unsigned u = __float_as_uint(x);
  u += 0x7FFFu + ((u >> 16) & 1u);   // round-to-nearest-even bf16
  return (u16)(u >> 16);
}
__device__ __forceinline__ float b2f(u16 v) { return __uint_as_float((unsigned)v << 16); }
__device__ __forceinline__ float sigmoidf_(float x) { return 1.f / (1.f + expf(-x)); }
__device__ __forceinline__ float siluf_(float x) { return x / (1.f + expf(-x)); }

// ---------------- f32 -> bf16 cast (vectorized) ----------------
__global__ __launch_bounds__(256) void cast_bf16(const float* __restrict__ in, u16* __restrict__ out, int n4) {
  int i = blockIdx.x * 256 + threadIdx.x;
  if (i >= n4) return;
  float4 v = ((const float4*)in)[i];
  ushort4 o; o.x = f2b(v.x); o.y = f2b(v.y); o.z = f2b(v.z); o.w = f2b(v.w);
  ((ushort4*)out)[i] = o;
}

// ---------------- concat W_in|W_gate -> bf16 [3072][768] + bias3072 ----------------
__global__ __launch_bounds__(256) void cast_ingate(const float* __restrict__ Wi, const float* __restrict__ Wg,
                                                   const float* __restrict__ bi, const float* __restrict__ bg,
                                                   u16* __restrict__ Wb, float* __restrict__ bias) {
  int i = blockIdx.x * 256 + threadIdx.x;   // < NIG*DM
  if (i >= NIG * DM) return;
  int r = i / DM, c = i % DM;
  Wb[i] = f2b(r < DI ? Wi[(size_t)r * DM + c] : Wg[(size_t)(r - DI) * DM + c]);
  if (i < NIG) bias[i] = (i < DI) ? bi[i] : bg[i - DI];
}

// ---------------- concat W_A/W_dt/W_B/W_C -> bf16 [64][DI] + bias64 ----------------
__global__ __launch_bounds__(256) void cast_wabcd(const float* __restrict__ WA, const float* __restrict__ Wdt,
                                                  const float* __restrict__ WB, const float* __restrict__ WC,
                                                  const float* __restrict__ bA, const float* __restrict__ bdt,
                                                  const float* __restrict__ bB, const float* __restrict__ bC,
                                                  u16* __restrict__ Wb, float* __restrict__ bias64) {
  int i = blockIdx.x * 256 + threadIdx.x;   // < 64*DI
  if (i >= 64 * DI) return;
  int r = i / DI, c = i % DI;
  const float* src = (r < 16) ? WA + (size_t)r * DI
                  : (r < 32) ? Wdt + (size_t)(r - 16) * DI
                  : (r < 48) ? WB + (size_t)(r - 32) * DI
                             : WC + (size_t)(r - 48) * DI;
  Wb[i] = f2b(src[c]);
  if (i < 64) bias64[i] = (i < 16) ? bA[i] : (i < 32) ? bdt[i - 16] : (i < 48) ? bB[i - 32] : bC[i - 48];
}

// ---------------- LayerNorm -> bf16 ----------------
__global__ __launch_bounds__(256) void ln_kernel(const float* __restrict__ x, const float* __restrict__ g,
                                                 const float* __restrict__ bb, u16* __restrict__ xn) {
  int m = blockIdx.x, tid = threadIdx.x;
  const float* xr = x + (size_t)m * DM;
  float v0 = xr[tid], v1 = xr[tid + 256], v2 = xr[tid + 512];
  float s  = v0 + v1 + v2;
  float s2 = fmaf(v0, v0, fmaf(v1, v1, v2 * v2));
  #pragma unroll
  for (int off = 32; off > 0; off >>= 1) { s += __shfl_down(s, off); s2 += __shfl_down(s2, off); }
  __shared__ float sh[8];
  int wave = tid >> 6, lane = tid & 63;
  if (lane == 0) { sh[wave] = s; sh[4 + wave] = s2; }
  __syncthreads();
  float S1 = sh[0] + sh[1] + sh[2] + sh[3];
  float S2 = sh[4] + sh[5] + sh[6] + sh[7];
  float mu = S1 * (1.f / DM);
  float var = S2 * (1.f / DM) - mu * mu;
  float rs = rsqrtf(var + 1e-5f);
  u16* o = xn + (size_t)m * DM;
  o[tid]       = f2b((v0 - mu) * rs * g[tid]       + bb[tid]);
  o[tid + 256] = f2b((v1 - mu) * rs * g[tid + 256] + bb[tid + 256]);
  o[tid + 512] = f2b((v2 - mu) * rs * g[tid + 512] + bb[tid + 512]);
}

// ---------------- bf16 MFMA NT-GEMM: acc = A[M][K] * B[N][K]^T + bias ----------------
// 512 threads, 8 waves, 128x128 block tile, 32x64 wave tile.
// MODE 0: C f32 = acc + bias + aux(resid, f32)
// MODE 1: u-mode: uv = b2f(auxb) * sigmoid(acc+bias); Cb = bf16(uv)
// MODE 2: Cb = bf16(acc + bias)
__device__ __forceinline__ void gll16(const void* g, void* l) {
  __builtin_amdgcn_global_load_lds((const __attribute__((address_space(1))) void*)g,
                                   (__attribute__((address_space(3))) void*)l, 16, 0, 0);
}

template <int MODE>
__global__ __launch_bounds__(512) void gemm_bt(const u16* __restrict__ A, const u16* __restrict__ B,
                                               const float* __restrict__ bias, const float* __restrict__ aux,
                                               const u16* __restrict__ auxb,
                                               float* __restrict__ C, u16* __restrict__ Cb,
                                               int M, int N, int K) {
  __shared__ __align__(16) u16 As[128 * 32];
  __shared__ __align__(16) u16 Bs[128 * 32];
  const int tid = threadIdx.x, wave = tid >> 6, lane = tid & 63;

  // XCD-aware bijective swizzle (nwg % 8 == 0 for all our grids)
  const int nbx = gridDim.x, nwg = nbx * gridDim.y;
  const int orig = blockIdx.y * nbx + blockIdx.x;
  const int cpx = nwg >> 3;
  const int swz = (orig & 7) * cpx + (orig >> 3);
  const int m0 = (swz / nbx) * 128, n0 = (swz % nbx) * 128;

  const int wm = (wave >> 1) * 32, wn = (wave & 1) * 64;
  const int fr = lane & 15, fq = lane >> 4;
  f32x4 acc[2][4] = {};

  // staging: LDS chunk c (linear dest) holds global k-chunk (c&3)^((c>>3)&3) of row c>>2
  const int c0 = tid;   // 512 chunks of 16B cover 128x32
  const u16* Ag0 = A + (size_t)(m0 + (c0 >> 2)) * K + ((c0 & 3) ^ ((c0 >> 3) & 3)) * 8;
  const u16* Bg0 = B + (size_t)(n0 + (c0 >> 2)) * K + ((c0 & 3) ^ ((c0 >> 3) & 3)) * 8;
  u16* lA0 = As + (wave * 64) * 8;          // wave-uniform LDS base; HW adds lane*16B
  u16* lB0 = Bs + (wave * 64) * 8;

  // swizzled ds_read offsets (u16 units), 2-way max per 8 bank-slots
  int offA[2], offB[4];
  #pragma unroll
  for (int i = 0; i < 2; ++i) {
    int ra = wm + i * 16 + fr;
    offA[i] = ra * 32 + (fq ^ ((ra >> 1) & 3)) * 8;
  }
  #pragma unroll
  for (int i = 0; i < 4; ++i) {
    int rb = wn + i * 16 + fr;
    offB[i] = rb * 32 + (fq ^ ((rb >> 1) & 3)) * 8;
  }

  for (int k0 = 0; k0 < K; k0 += 32) {
    gll16(Ag0 + k0, lA0);
    gll16(Bg0 + k0, lB0);
    __syncthreads();
    short8 av[2], bv[4];
    #pragma unroll
    for (int i = 0; i < 2; ++i) av[i] = *(const short8*)(As + offA[i]);
    #pragma unroll
    for (int i = 0; i < 4; ++i) bv[i] = *(const short8*)(Bs + offB[i]);
    #pragma unroll
    for (int mi = 0; mi < 2; ++mi)
      #pragma unroll
      for (int ni = 0; ni < 4; ++ni)
        acc[mi][ni] = __builtin_amdgcn_mfma_f32_16x16x32_bf16(av[mi], bv[ni], acc[mi][ni], 0, 0, 0);
    __syncthreads();
  }

  #pragma unroll
  for (int ni = 0; ni < 4; ++ni) {
    int col = n0 + wn + ni * 16 + fr;
    float bv_ = bias[col];
    #pragma unroll
    for (int mi = 0; mi < 2; ++mi) {
      int row = m0 + wm + mi * 16 + fq * 4;
      #pragma unroll
      for (int j = 0; j < 4; ++j) {
        size_t off = (size_t)(row + j) * N + col;
        float z = acc[mi][ni][j] + bv_;
        if (MODE == 0) {
          C[off] = z + aux[off];
        } else if (MODE == 1) {
          Cb[off] = f2b(b2f(auxb[off]) * sigmoidf_(z));
        } else {
          Cb[off] = f2b(z);
        }
      }
    }
  }
}

// ---------------- abcd GEMM: Z = ub[M][K] * Wabcd[64][K]^T; fused dec/Bm/Cm epilogue ----------------
__global__ __launch_bounds__(256) void gemm_abcd(const u16* __restrict__ A, const u16* __restrict__ B,
                                                 const float* __restrict__ bias64,
                                                 float* __restrict__ dec, float* __restrict__ Bm,
                                                 float* __restrict__ Cm, int M, int K) {
  __shared__ __align__(16) u16 As[64 * 32];
  __shared__ __align__(16) u16 Bs[64 * 32];
  const int tid = threadIdx.x, wave = tid >> 6, lane = tid & 63;
  const int m0 = blockIdx.x * 64;
  const int wm = wave * 16;
  const int fr = lane & 15, fq = lane >> 4;
  f32x4 acc[4] = {};

  const int c0 = tid;   // 256 chunks of 16B cover 64x32
  const u16* Ag0 = A + (size_t)(m0 + (c0 >> 2)) * K + (c0 & 3) * 8;
  const u16* Bg0 = B + (size_t)(c0 >> 2) * K + (c0 & 3) * 8;
  u16* lA0 = As + (wave * 64) * 8;
  u16* lB0 = Bs + (wave * 64) * 8;

  for (int k0 = 0; k0 < K; k0 += 32) {
    gll16(Ag0 + k0, lA0);
    gll16(Bg0 + k0, lB0);
    __syncthreads();
    short8 av = *(const short8*)(As + (wm + fr) * 32 + fq * 8);
    short8 bv[4];
    #pragma unroll
    for (int i = 0; i < 4; ++i) bv[i] = *(const short8*)(Bs + (i * 16 + fr) * 32 + fq * 8);
    #pragma unroll
    for (int ni = 0; ni < 4; ++ni)
      acc[ni] = __builtin_amdgcn_mfma_f32_16x16x32_bf16(av, bv[ni], acc[ni], 0, 0, 0);
    __syncthreads();
  }

  // cols: ni=0 -> zA[fr], ni=1 -> zdt[fr], ni=2 -> B[fr], ni=3 -> C[fr]; same lane holds all four.
  float bA_ = bias64[fr], bDt_ = bias64[16 + fr], bB_ = bias64[32 + fr], bC_ = bias64[48 + fr];
  #pragma unroll
  for (int j = 0; j < 4; ++j) {
    int row = m0 + wm + fq * 4 + j;
    size_t o = (size_t)row * NST + fr;
    float zA = acc[0][j] + bA_, zDt = acc[1][j] + bDt_;
    dec[o] = expf(-expf(zA + zDt));
    Bm[o]  = acc[2][j] + bB_;
    Cm[o]  = acc[3][j] + bC_;
  }
}

// ---------------- depthwise causal conv (k=4) + bias + silu; reads bf16 xpg, writes bf16 ----------------
__global__ __launch_bounds__(256) void conv_silu(const u16* __restrict__ xpg, const float* __restrict__ cw,
                                                 const float* __restrict__ cb, u16* __restrict__ xab) {
  int idx = blockIdx.x * 256 + threadIdx.x;   // < NTOK*DI
  int d = idx % DI;
  int token = idx / DI;
  int t = token % SEQ;
  size_t base = (size_t)token * NIG + d;
  float4 w = ((const float4*)cw)[d];          // conv_w[d][0][0..3]
  float acc = cb[d];
  if (t >= 3) acc = fmaf(b2f(xpg[base - 3 * NIG]), w.x, acc);
  if (t >= 2) acc = fmaf(b2f(xpg[base - 2 * NIG]), w.y, acc);
  if (t >= 1) acc = fmaf(b2f(xpg[base - 1 * NIG]), w.z, acc);
  acc = fmaf(b2f(xpg[base]), w.w, acc);
  xab[idx] = f2b(siluf_(acc));
}

// ---------------- chunked selective scan ----------------
// phase1: per-chunk local scan from h=0 -> lend[c][b][d][16]; P[c][b][16]=prod(dec)
__global__ __launch_bounds__(256) void scan_phase1(const u16* __restrict__ ub, const float* __restrict__ dec,
                                                   const float* __restrict__ Bm, float* __restrict__ lend,
                                                   float* __restrict__ P) {
  __shared__ float dl[LCH * NST], bl[LCH * NST];
  int bid = blockIdx.x;
  int dblk = bid % 6, b = (bid / 6) % BATCH, c = bid / (6 * BATCH);
  int d = dblk * 256 + threadIdx.x;
  int t0 = c * LCH;
  size_t base16 = (size_t)(b * SEQ + t0) * NST;
  for (int i = threadIdx.x; i < LCH * NST; i += 256) { dl[i] = dec[base16 + i]; bl[i] = Bm[base16 + i]; }
  __syncthreads();
  float h[NST];
  #pragma unroll
  for (int n = 0; n < NST; ++n) h[n] = 0.f;
  const u16* up = ub + (size_t)(b * SEQ + t0) * DI + d;
  for (int t = 0; t < LCH; ++t) {
    float uu = b2f(up[(size_t)t * DI]);
    #pragma unroll
    for (int n = 0; n < NST; ++n) h[n] = fmaf(h[n], dl[t * NST + n], bl[t * NST + n] * uu);
  }
  float* lo = lend + ((size_t)(c * BATCH + b) * DI + d) * NST;
  ((float4*)lo)[0] = make_float4(h[0], h[1], h[2], h[3]);
  ((float4*)lo)[1] = make_float4(h[4], h[5], h[6], h[7]);
  ((float4*)lo)[2] = make_float4(h[8], h[9], h[10], h[11]);
  ((float4*)lo)[3] = make_float4(h[12], h[13], h[14], h[15]);
  if (dblk == 0 && threadIdx.x < NST) {
    float pr = 1.f;
    for (int t = 0; t < LCH; ++t) pr *= dl[t * NST + threadIdx.x];
    P[(size_t)(c * BATCH + b) * NST + threadIdx.x] = pr;
  }
}

// phase2: cross-chunk scan; Hin[c] = state entering chunk c
__global__ __launch_bounds__(256) void scan_phase2(const float* __restrict__ lend, const float* __restrict__ P,
                                                   float* __restrict__ Hin) {
  int flat = blockIdx.x * 256 + threadIdx.x;  // < BATCH*DI
  int d = flat % DI, b = flat / DI;
  float h[NST];
  #pragma unroll
  for (int n = 0; n < NST; ++n) h[n] = 0.f;
  for (int c = 0; c < NCH; ++c) {
    size_t idx = ((size_t)(c * BATCH + b) * DI + d) * NST;
    float4* hp = (float4*)(Hin + idx);
    hp[0] = make_float4(h[0], h[1], h[2], h[3]);
    hp[1] = make_float4(h[4], h[5], h[6], h[7]);
    hp[2] = make_float4(h[8], h[9], h[10], h[11]);
    hp[3] = make_float4(h[12], h[13], h[14], h[15]);
    const float4* le = (const float4*)(lend + idx);
    const float* pc = P + (size_t)(c * BATCH + b) * NST;
    float4 l0 = le[0], l1 = le[1], l2 = le[2], l3 = le[3];
    h[0] = fmaf(pc[0],  h[0],  l0.x); h[1] = fmaf(pc[1],  h[1],  l0.y);
    h[2] = fmaf(pc[2],  h[2],  l0.z); h[3] = fmaf(pc[3],  h[3],  l0.w);
    h[4] = fmaf(pc[4],  h[4],  l1.x); h[5] = fmaf(pc[5],  h[5],  l1.y);
    h[6] = fmaf(pc[6],  h[6],  l1.z); h[7] = fmaf(pc[7],  h[7],  l1.w);
    h[8] = fmaf(pc[8],  h[8],  l2.x); h[9] = fmaf(pc[9],  h[9],  l2.y);
    h[10] = fmaf(pc[10], h[10], l2.z); h[11] = fmaf(pc[11], h[11], l2.w);
    h[12] = fmaf(pc[12], h[12], l3.x); h[13] = fmaf(pc[13], h[13], l3.y);
    h[14] = fmaf(pc[14], h[14], l3.z); h[15] = fmaf(pc[15], h[15], l3.w);
  }
}

// phase3: replay chunk from Hin, emit gy = bf16(silu(gate) * y); gate is cols DI..2DI of xpg
__global__ __launch_bounds__(256) void scan_phase3(const u16* __restrict__ ub, const float* __restrict__ dec,
                                                   const float* __restrict__ Bm, const float* __restrict__ Cm,
                                                   const float* __restrict__ Hin, const u16* __restrict__ xpg,
                                                   u16* __restrict__ gy) {
  __shared__ float dl[LCH * NST], bl[LCH * NST], cl[LCH * NST];
  int bid = blockIdx.x;
  int dblk = bid % 6, b = (bid / 6) % BATCH, c = bid / (6 * BATCH);
  int d = dblk * 256 + threadIdx.x;
  int t0 = c * LCH;
  size_t base16 = (size_t)(b * SEQ + t0) * NST;
  for (int i = threadIdx.x; i < LCH * NST; i += 256) {
    dl[i] = dec[base16 + i]; bl[i] = Bm[base16 + i]; cl[i] = Cm[base16 + i];
  }
  __syncthreads();
  float h[NST];
  const float4* hi = (const float4*)(Hin + ((size_t)(c * BATCH + b) * DI + d) * NST);
  float4 h0 = hi[0], h1 = hi[1], h2 = hi[2], h3 = hi[3];
  h[0]=h0.x; h[1]=h0.y; h[2]=h0.z; h[3]=h0.w; h[4]=h1.x; h[5]=h1.y; h[6]=h1.z; h[7]=h1.w;
  h[8]=h2.x; h[9]=h2.y; h[10]=h2.z; h[11]=h2.w; h[12]=h3.x; h[13]=h3.y; h[14]=h3.z; h[15]=h3.w;
  const u16* up = ub + (size_t)(b * SEQ + t0) * DI + d;
  const u16* gp = xpg + (size_t)(b * SEQ + t0) * NIG + DI + d;
  u16* yp = gy + (size_t)(b * SEQ + t0) * DI + d;
  for (int t = 0; t < LCH; ++t) {
    float uu = b2f(up[(size_t)t * DI]);
    float acc = 0.f;
    #pragma unroll
    for (int n = 0; n < NST; ++n) {
      h[n] = fmaf(h[n], dl[t * NST + n], bl[t * NST + n] * uu);
      acc = fmaf(h[n], cl[t * NST + n], acc);
    }
    float g = b2f(gp[(size_t)t * NIG]);
    yp[(size_t)t * DI] = f2b(siluf_(g) * acc);
  }
}

extern "C" void kernel_launch(void* const* d_in, const int* in_sizes, int n_in,
                              void* d_out, int out_size, void* d_ws, size_t ws_size,
                              hipStream_t stream) {
  const float* x      = (const float*)d_in[0];
  const float* ln_g   = (const float*)d_in[1];
  const float* ln_b   = (const float*)d_in[2];
  const float* W_in   = (const float*)d_in[3];
  const float* b_in   = (const float*)d_in[4];
  const float* conv_w = (const float*)d_in[5];
  const float* conv_b = (const float*)d_in[6];
  const float* W_A    = (const float*)d_in[7];
  const float* b_A    = (const float*)d_in[8];
  const float* W_B    = (const float*)d_in[9];
  const float* b_B    = (const float*)d_in[10];
  const float* W_C    = (const float*)d_in[11];
  const float* b_C    = (const float*)d_in[12];
  const float* W_dt   = (const float*)d_in[13];
  const float* b_dt   = (const float*)d_in[14];
  const float* W_S    = (const float*)d_in[15];
  const float* b_S    = (const float*)d_in[16];
  const float* W_gate = (const float*)d_in[17];
  const float* b_gate = (const float*)d_in[18];
  const float* W_out  = (const float*)d_in[19];
  const float* b_out  = (const float*)d_in[20];
  float* out = (float*)d_out;

  char* p = (char*)d_ws;
  auto alloc = [&](size_t bytes) { char* r = p; p += (bytes + 255) & ~(size_t)255; return r; };
  u16*   Wigb    = (u16*)alloc((size_t)NIG * DM * 2);   // [3072][768] = W_in | W_gate
  float* biasig  = (float*)alloc((size_t)NIG * 4);
  u16*   WSb     = (u16*)alloc((size_t)DI * DI * 2);    // first half of W_S only
  u16*   Woutb   = (u16*)alloc((size_t)DM * DI * 2);
  u16*   Wabcd   = (u16*)alloc((size_t)64 * DI * 2);
  float* bias64  = (float*)alloc(64 * 4);
  u16*   xnb     = (u16*)alloc((size_t)NTOK * DM * 2);
  u16*   xpg     = (u16*)alloc((size_t)NTOK * NIG * 2); // [tok][3072]: xp | gate (bf16)
  u16*   xab     = (u16*)alloc((size_t)NTOK * DI * 2);  // silu(conv) bf16; reused as gy
  u16*   ub      = (u16*)alloc((size_t)NTOK * DI * 2);  // u bf16
  float* decb    = (float*)alloc((size_t)NTOK * NST * 4);
  float* Bmb     = (float*)alloc((size_t)NTOK * NST * 4);
  float* Cmb     = (float*)alloc((size_t)NTOK * NST * 4);
  float* lend    = (float*)alloc((size_t)NCH * BATCH * DI * NST * 4);
  float* Hin     = (float*)alloc((size_t)NCH * BATCH * DI * NST * 4);
  float* P       = (float*)alloc((size_t)NCH * BATCH * NST * 4);
  u16* gy = xab;

  // weight prep
  cast_ingate<<<(NIG * DM + 255) / 256, 256, 0, stream>>>(W_in, W_gate, b_in, b_gate, Wigb, biasig);
  cast_bf16<<<(DI * DI / 4 + 255) / 256, 256, 0, stream>>>(W_S, WSb, DI * DI / 4);
  cast_bf16<<<(DM * DI / 4 + 255) / 256, 256, 0, stream>>>(W_out, Woutb, DM * DI / 4);
  cast_wabcd<<<(64 * DI + 255) / 256, 256, 0, stream>>>(W_A, W_dt, W_B, W_C, b_A, b_dt, b_B, b_C, Wabcd, bias64);

  ln_kernel<<<NTOK, 256, 0, stream>>>(x, ln_g, ln_b, xnb);

  // fused in|gate GEMM -> xpg bf16
  gemm_bt<2><<<dim3(NIG / 128, NTOK / 128), 512, 0, stream>>>(xnb, Wigb, biasig, nullptr, nullptr,
                                                              nullptr, xpg, NTOK, NIG, DM);

  conv_silu<<<NTOK * DI / 256, 256, 0, stream>>>(xpg, conv_w, conv_b, xab);

  // S GEMM with fused u = xa * sigmoid(Sp) -> ub bf16 (aux = xab, same buffer as A operand)
  gemm_bt<1><<<dim3(DI / 128, NTOK / 128), 512, 0, stream>>>(xab, WSb, b_S, nullptr, xab,
                                                             nullptr, ub, NTOK, DI, DI);

  gemm_abcd<<<NTOK / 64, 256, 0, stream>>>(ub, Wabcd, bias64, decb, Bmb, Cmb, NTOK, DI);

  scan_phase1<<<NCH * BATCH * (DI / 256), 256, 0, stream>>>(ub, decb, Bmb, lend, P);
  scan_phase2<<<BATCH * DI / 256, 256, 0, stream>>>(lend, P, Hin);
  scan_phase3<<<NCH * BATCH * (DI / 256), 256, 0, stream>>>(ub, decb, Bmb, Cmb, Hin, xpg, gy);

  // out GEMM + residual (f32 out)
  gemm_bt<0><<<dim3(DM / 128, NTOK / 128), 512, 0, stream>>>(gy, Woutb, b_out, x, nullptr,
                                                             out, nullptr, NTOK, DM, DI);
}

// Round 7
// 225.391 us; speedup vs baseline: 2.0785x; 1.1469x over previous
//
#include <hip/hip_runtime.h>

// BayesianMambaBlock on MI355X (gfx950).
// LN -> fused (in|gate) GEMM (bf16 out) -> conv+silu (bf16) -> S GEMM (fused u, bf16 out) ->
// abcd GEMM (fused dec/B/C) -> chunked scan (phase3 fused gate) -> out GEMM (+resid, f32).
// gemm_bt/gemm_abcd: 2-phase double-buffered LDS (1 full-drain barrier per K-step, prefetch depth 1),
// chunk-XOR LDS swizzle (pre-swizzled global source, linear LDS dest), XCD-aware block swizzle.

typedef unsigned short u16;
using short8 = __attribute__((ext_vector_type(8))) short;
using f32x4  = __attribute__((ext_vector_type(4))) float;

#define BATCH 2
#define SEQ   2048
#define DM    768
#define DI    1536
#define NIG   (2*DI)        // fused in+gate width 3072
#define NST   16
#define LCH   64
#define NCH   32
#define NTOK  (BATCH*SEQ)   // 4096

__device__ __forceinline__ u16 f2b(float x) {
  unsigned u = __float_as_uint(x);
  u += 0x7FFFu + ((u >> 16) & 1u);   // round-to-nearest-even bf16
  return (u16)(u >> 16);
}
__device__ __forceinline__ float b2f(u16 v) { return __uint_as_float((unsigned)v << 16); }
__device__ __forceinline__ float sigmoidf_(float x) { return 1.f / (1.f + expf(-x)); }
__device__ __forceinline__ float siluf_(float x) { return x / (1.f + expf(-x)); }

// ---------------- f32 -> bf16 cast (vectorized) ----------------
__global__ __launch_bounds__(256) void cast_bf16(const float* __restrict__ in, u16* __restrict__ out, int n4) {
  int i = blockIdx.x * 256 + threadIdx.x;
  if (i >= n4) return;
  float4 v = ((const float4*)in)[i];
  ushort4 o; o.x = f2b(v.x); o.y = f2b(v.y); o.z = f2b(v.z); o.w = f2b(v.w);
  ((ushort4*)out)[i] = o;
}

// ---------------- concat W_in|W_gate -> bf16 [3072][768] + bias3072 ----------------
__global__ __launch_bounds__(256) void cast_ingate(const float* __restrict__ Wi, const float* __restrict__ Wg,
                                                   const float* __restrict__ bi, const float* __restrict__ bg,
                                                   u16* __restrict__ Wb, float* __restrict__ bias) {
  int i = blockIdx.x * 256 + threadIdx.x;   // < NIG*DM
  if (i >= NIG * DM) return;
  int r = i / DM, c = i % DM;
  Wb[i] = f2b(r < DI ? Wi[(size_t)r * DM + c] : Wg[(size_t)(r - DI) * DM + c]);
  if (i < NIG) bias[i] = (i < DI) ? bi[i] : bg[i - DI];
}

// ---------------- concat W_A/W_dt/W_B/W_C -> bf16 [64][DI] + bias64 ----------------
__global__ __launch_bounds__(256) void cast_wabcd(const float* __restrict__ WA, const float* __restrict__ Wdt,
                                                  const float* __restrict__ WB, const float* __restrict__ WC,
                                                  const float* __restrict__ bA, const float* __restrict__ bdt,
                                                  const float* __restrict__ bB, const float* __restrict__ bC,
                                                  u16* __restrict__ Wb, float* __restrict__ bias64) {
  int i = blockIdx.x * 256 + threadIdx.x;   // < 64*DI
  if (i >= 64 * DI) return;
  int r = i / DI, c = i % DI;
  const float* src = (r < 16) ? WA + (size_t)r * DI
                  : (r < 32) ? Wdt + (size_t)(r - 16) * DI
                  : (r < 48) ? WB + (size_t)(r - 32) * DI
                             : WC + (size_t)(r - 48) * DI;
  Wb[i] = f2b(src[c]);
  if (i < 64) bias64[i] = (i < 16) ? bA[i] : (i < 32) ? bdt[i - 16] : (i < 48) ? bB[i - 32] : bC[i - 48];
}

// ---------------- LayerNorm -> bf16 ----------------
__global__ __launch_bounds__(256) void ln_kernel(const float* __restrict__ x, const float* __restrict__ g,
                                                 const float* __restrict__ bb, u16* __restrict__ xn) {
  int m = blockIdx.x, tid = threadIdx.x;
  const float* xr = x + (size_t)m * DM;
  float v0 = xr[tid], v1 = xr[tid + 256], v2 = xr[tid + 512];
  float s  = v0 + v1 + v2;
  float s2 = fmaf(v0, v0, fmaf(v1, v1, v2 * v2));
  #pragma unroll
  for (int off = 32; off > 0; off >>= 1) { s += __shfl_down(s, off); s2 += __shfl_down(s2, off); }
  __shared__ float sh[8];
  int wave = tid >> 6, lane = tid & 63;
  if (lane == 0) { sh[wave] = s; sh[4 + wave] = s2; }
  __syncthreads();
  float S1 = sh[0] + sh[1] + sh[2] + sh[3];
  float S2 = sh[4] + sh[5] + sh[6] + sh[7];
  float mu = S1 * (1.f / DM);
  float var = S2 * (1.f / DM) - mu * mu;
  float rs = rsqrtf(var + 1e-5f);
  u16* o = xn + (size_t)m * DM;
  o[tid]       = f2b((v0 - mu) * rs * g[tid]       + bb[tid]);
  o[tid + 256] = f2b((v1 - mu) * rs * g[tid + 256] + bb[tid + 256]);
  o[tid + 512] = f2b((v2 - mu) * rs * g[tid + 512] + bb[tid + 512]);
}

// ---------------- bf16 MFMA NT-GEMM: acc = A[M][K] * B[N][K]^T + bias ----------------
// 512 threads, 8 waves, 128x128 block tile, 32x64 wave tile, 2-phase double-buffered staging.
// MODE 0: C f32 = acc + bias + aux(resid, f32)
// MODE 1: u-mode: uv = b2f(auxb) * sigmoid(acc+bias); Cb = bf16(uv)
// MODE 2: Cb = bf16(acc + bias)
__device__ __forceinline__ void gll16(const void* g, void* l) {
  __builtin_amdgcn_global_load_lds((const __attribute__((address_space(1))) void*)g,
                                   (__attribute__((address_space(3))) void*)l, 16, 0, 0);
}

template <int MODE>
__global__ __launch_bounds__(512) void gemm_bt(const u16* __restrict__ A, const u16* __restrict__ B,
                                               const float* __restrict__ bias, const float* __restrict__ aux,
                                               const u16* __restrict__ auxb,
                                               float* __restrict__ C, u16* __restrict__ Cb,
                                               int M, int N, int K) {
  __shared__ __align__(16) u16 As[2][128 * 32];
  __shared__ __align__(16) u16 Bs[2][128 * 32];
  const int tid = threadIdx.x, wave = tid >> 6, lane = tid & 63;

  // XCD-aware bijective swizzle (nwg % 8 == 0 for all our grids)
  const int nbx = gridDim.x, nwg = nbx * gridDim.y;
  const int orig = blockIdx.y * nbx + blockIdx.x;
  const int cpx = nwg >> 3;
  const int swz = (orig & 7) * cpx + (orig >> 3);
  const int m0 = (swz / nbx) * 128, n0 = (swz % nbx) * 128;

  const int wm = (wave >> 1) * 32, wn = (wave & 1) * 64;
  const int fr = lane & 15, fq = lane >> 4;
  f32x4 acc[2][4] = {};

  // staging: LDS chunk c (linear dest) holds global k-chunk (c&3)^((c>>3)&3) of row c>>2
  const int c0 = tid;   // 512 chunks of 16B cover 128x32
  const u16* Ag0 = A + (size_t)(m0 + (c0 >> 2)) * K + ((c0 & 3) ^ ((c0 >> 3) & 3)) * 8;
  const u16* Bg0 = B + (size_t)(n0 + (c0 >> 2)) * K + ((c0 & 3) ^ ((c0 >> 3) & 3)) * 8;
  const int lofs = (wave * 64) * 8;   // wave-uniform LDS base; HW adds lane*16B

  // swizzled ds_read offsets (u16 units), 2-way max per 8 bank-slots
  int offA[2], offB[4];
  #pragma unroll
  for (int i = 0; i < 2; ++i) {
    int ra = wm + i * 16 + fr;
    offA[i] = ra * 32 + (fq ^ ((ra >> 1) & 3)) * 8;
  }
  #pragma unroll
  for (int i = 0; i < 4; ++i) {
    int rb = wn + i * 16 + fr;
    offB[i] = rb * 32 + (fq ^ ((rb >> 1) & 3)) * 8;
  }

  const int nk = K >> 5;
  // prologue: stage tile 0 into buf 0
  gll16(Ag0, (u16*)As[0] + lofs);
  gll16(Bg0, (u16*)Bs[0] + lofs);

  for (int t = 0; t < nk; ++t) {
    __syncthreads();   // publishes stage(t) (full drain) + retires all reads of buf[(t+1)&1]
    if (t + 1 < nk) {  // issue next tile; drains at NEXT iteration's barrier (overlaps compute below)
      gll16(Ag0 + (t + 1) * 32, (u16*)As[(t + 1) & 1] + lofs);
      gll16(Bg0 + (t + 1) * 32, (u16*)Bs[(t + 1) & 1] + lofs);
    }
    const u16* as = As[t & 1];
    const u16* bs = Bs[t & 1];
    short8 av[2], bv[4];
    #pragma unroll
    for (int i = 0; i < 2; ++i) av[i] = *(const short8*)(as + offA[i]);
    #pragma unroll
    for (int i = 0; i < 4; ++i) bv[i] = *(const short8*)(bs + offB[i]);
    #pragma unroll
    for (int mi = 0; mi < 2; ++mi)
      #pragma unroll
      for (int ni = 0; ni < 4; ++ni)
        acc[mi][ni] = __builtin_amdgcn_mfma_f32_16x16x32_bf16(av[mi], bv[ni], acc[mi][ni], 0, 0, 0);
  }

  #pragma unroll
  for (int ni = 0; ni < 4; ++ni) {
    int col = n0 + wn + ni * 16 + fr;
    float bv_ = bias[col];
    #pragma unroll
    for (int mi = 0; mi < 2; ++mi) {
      int row = m0 + wm + mi * 16 + fq * 4;
      #pragma unroll
      for (int j = 0; j < 4; ++j) {
        size_t off = (size_t)(row + j) * N + col;
        float z = acc[mi][ni][j] + bv_;
        if (MODE == 0) {
          C[off] = z + aux[off];
        } else if (MODE == 1) {
          Cb[off] = f2b(b2f(auxb[off]) * sigmoidf_(z));
        } else {
          Cb[off] = f2b(z);
        }
      }
    }
  }
}

// ---------------- abcd GEMM: Z = ub[M][K] * Wabcd[64][K]^T; fused dec/Bm/Cm epilogue ----------------
// 256 threads, 64x64 tile, BK=64, 2-phase double-buffered. Chunk-XOR swizzle (8 chunks/row).
__global__ __launch_bounds__(256) void gemm_abcd(const u16* __restrict__ A, const u16* __restrict__ B,
                                                 const float* __restrict__ bias64,
                                                 float* __restrict__ dec, float* __restrict__ Bm,
                                                 float* __restrict__ Cm, int M, int K) {
  __shared__ __align__(16) u16 As[2][64 * 64];
  __shared__ __align__(16) u16 Bs[2][64 * 64];
  const int tid = threadIdx.x, wave = tid >> 6, lane = tid & 63;
  const int m0 = blockIdx.x * 64;
  const int wm = wave * 16;
  const int fr = lane & 15, fq = lane >> 4;
  f32x4 acc[4] = {};

  // 512 chunks of 16B cover 64x64; chunk c: row=c>>3, LDS slot c&7 holds k-chunk (c&7)^(row&7)
  const int c0 = tid, c1 = tid + 256;
  const u16* Ag0 = A + (size_t)(m0 + (c0 >> 3)) * K + ((c0 & 7) ^ ((c0 >> 3) & 7)) * 8;
  const u16* Ag1 = A + (size_t)(m0 + (c1 >> 3)) * K + ((c1 & 7) ^ ((c1 >> 3) & 7)) * 8;
  const u16* Bg0 = B + (size_t)(c0 >> 3) * K + ((c0 & 7) ^ ((c0 >> 3) & 7)) * 8;
  const u16* Bg1 = B + (size_t)(c1 >> 3) * K + ((c1 & 7) ^ ((c1 >> 3) & 7)) * 8;
  const int lo0 = (wave * 64) * 8;          // chunks [0,256): base + lane*16B
  const int lo1 = (256 + wave * 64) * 8;    // chunks [256,512)

  // ds_read offsets: row r, k-chunk q=kk*4+fq stored at slot q^(r&7)
  int offAv[2], offBv[2][4];
  {
    int r = wm + fr;
    #pragma unroll
    for (int kk = 0; kk < 2; ++kk) offAv[kk] = r * 64 + ((kk * 4 + fq) ^ (r & 7)) * 8;
    #pragma unroll
    for (int i = 0; i < 4; ++i) {
      int rb = i * 16 + fr;
      #pragma unroll
      for (int kk = 0; kk < 2; ++kk) offBv[kk][i] = rb * 64 + ((kk * 4 + fq) ^ (rb & 7)) * 8;
    }
  }

  const int nk = K >> 6;   // 24
  gll16(Ag0, (u16*)As[0] + lo0);
  gll16(Ag1, (u16*)As[0] + lo1);
  gll16(Bg0, (u16*)Bs[0] + lo0);
  gll16(Bg1, (u16*)Bs[0] + lo1);

  for (int t = 0; t < nk; ++t) {
    __syncthreads();
    if (t + 1 < nk) {
      int ko = (t + 1) * 64;
      gll16(Ag0 + ko, (u16*)As[(t + 1) & 1] + lo0);
      gll16(Ag1 + ko, (u16*)As[(t + 1) & 1] + lo1);
      gll16(Bg0 + ko, (u16*)Bs[(t + 1) & 1] + lo0);
      gll16(Bg1 + ko, (u16*)Bs[(t + 1) & 1] + lo1);
    }
    const u16* as = As[t & 1];
    const u16* bs = Bs[t & 1];
    #pragma unroll
    for (int kk = 0; kk < 2; ++kk) {
      short8 av = *(const short8*)(as + offAv[kk]);
      short8 bv[4];
      #pragma unroll
      for (int i = 0; i < 4; ++i) bv[i] = *(const short8*)(bs + offBv[kk][i]);
      #pragma unroll
      for (int ni = 0; ni < 4; ++ni)
        acc[ni] = __builtin_amdgcn_mfma_f32_16x16x32_bf16(av, bv[ni], acc[ni], 0, 0, 0);
    }
  }

  // cols: ni=0 -> zA[fr], ni=1 -> zdt[fr], ni=2 -> B[fr], ni=3 -> C[fr]; same lane holds all four.
  float bA_ = bias64[fr], bDt_ = bias64[16 + fr], bB_ = bias64[32 + fr], bC_ = bias64[48 + fr];
  #pragma unroll
  for (int j = 0; j < 4; ++j) {
    int row = m0 + wm + fq * 4 + j;
    size_t o = (size_t)row * NST + fr;
    float zA = acc[0][j] + bA_, zDt = acc[1][j] + bDt_;
    dec[o] = expf(-expf(zA + zDt));
    Bm[o]  = acc[2][j] + bB_;
    Cm[o]  = acc[3][j] + bC_;
  }
}

// ---------------- depthwise causal conv (k=4) + bias + silu; reads bf16 xpg, writes bf16 ----------------
__global__ __launch_bounds__(256) void conv_silu(const u16* __restrict__ xpg, const float* __restrict__ cw,
                                                 const float* __restrict__ cb, u16* __restrict__ xab) {
  int idx = blockIdx.x * 256 + threadIdx.x;   // < NTOK*DI
  int d = idx % DI;
  int token = idx / DI;
  int t = token % SEQ;
  size_t base = (size_t)token * NIG + d;
  float4 w = ((const float4*)cw)[d];          // conv_w[d][0][0..3]
  float acc = cb[d];
  if (t >= 3) acc = fmaf(b2f(xpg[base - 3 * NIG]), w.x, acc);
  if (t >= 2) acc = fmaf(b2f(xpg[base - 2 * NIG]), w.y, acc);
  if (t >= 1) acc = fmaf(b2f(xpg[base - 1 * NIG]), w.z, acc);
  acc = fmaf(b2f(xpg[base]), w.w, acc);
  xab[idx] = f2b(siluf_(acc));
}

// ---------------- chunked selective scan ----------------
// phase1: per-chunk local scan from h=0 -> lend[c][b][d][16]; P[c][b][16]=prod(dec)
__global__ __launch_bounds__(256) void scan_phase1(const u16* __restrict__ ub, const float* __restrict__ dec,
                                                   const float* __restrict__ Bm, float* __restrict__ lend,
                                                   float* __restrict__ P) {
  __shared__ float dl[LCH * NST], bl[LCH * NST];
  int bid = blockIdx.x;
  int dblk = bid % 6, b = (bid / 6) % BATCH, c = bid / (6 * BATCH);
  int d = dblk * 256 + threadIdx.x;
  int t0 = c * LCH;
  size_t base16 = (size_t)(b * SEQ + t0) * NST;
  for (int i = threadIdx.x; i < LCH * NST; i += 256) { dl[i] = dec[base16 + i]; bl[i] = Bm[base16 + i]; }
  __syncthreads();
  float h[NST];
  #pragma unroll
  for (int n = 0; n < NST; ++n) h[n] = 0.f;
  const u16* up = ub + (size_t)(b * SEQ + t0) * DI + d;
  for (int t = 0; t < LCH; ++t) {
    float uu = b2f(up[(size_t)t * DI]);
    #pragma unroll
    for (int n = 0; n < NST; ++n) h[n] = fmaf(h[n], dl[t * NST + n], bl[t * NST + n] * uu);
  }
  float* lo = lend + ((size_t)(c * BATCH + b) * DI + d) * NST;
  ((float4*)lo)[0] = make_float4(h[0], h[1], h[2], h[3]);
  ((float4*)lo)[1] = make_float4(h[4], h[5], h[6], h[7]);
  ((float4*)lo)[2] = make_float4(h[8], h[9], h[10], h[11]);
  ((float4*)lo)[3] = make_float4(h[12], h[13], h[14], h[15]);
  if (dblk == 0 && threadIdx.x < NST) {
    float pr = 1.f;
    for (int t = 0; t < LCH; ++t) pr *= dl[t * NST + threadIdx.x];
    P[(size_t)(c * BATCH + b) * NST + threadIdx.x] = pr;
  }
}

// phase2: cross-chunk scan, parallel over (b,d,n); Hin[c] = state entering chunk c
__global__ __launch_bounds__(256) void scan_phase2(const float* __restrict__ lend, const float* __restrict__ P,
                                                   float* __restrict__ Hin) {
  int flat = blockIdx.x * 256 + threadIdx.x;  // < BATCH*DI*NST
  int n = flat & 15;
  int d = (flat >> 4) % DI;
  int b = flat / (DI * NST);
  float h = 0.f;
  for (int c = 0; c < NCH; ++c) {
    size_t idx = ((size_t)(c * BATCH + b) * DI + d) * NST + n;
    Hin[idx] = h;
    h = fmaf(P[(size_t)(c * BATCH + b) * NST + n], h, lend[idx]);
  }
}

// phase3: replay chunk from Hin, emit gy = bf16(silu(gate) * y); gate is cols DI..2DI of xpg
__global__ __launch_bounds__(256) void scan_phase3(const u16* __restrict__ ub, const float* __restrict__ dec,
                                                   const float* __restrict__ Bm, const float* __restrict__ Cm,
                                                   const float* __restrict__ Hin, const u16* __restrict__ xpg,
                                                   u16* __restrict__ gy) {
  __shared__ float dl[LCH * NST], bl[LCH * NST], cl[LCH * NST];
  int bid = blockIdx.x;
  int dblk = bid % 6, b = (bid / 6) % BATCH, c = bid / (6 * BATCH);
  int d = dblk * 256 + threadIdx.x;
  int t0 = c * LCH;
  size_t base16 = (size_t)(b * SEQ + t0) * NST;
  for (int i = threadIdx.x; i < LCH * NST; i += 256) {
    dl[i] = dec[base16 + i]; bl[i] = Bm[base16 + i]; cl[i] = Cm[base16 + i];
  }
  __syncthreads();
  float h[NST];
  const float4* hi = (const float4*)(Hin + ((size_t)(c * BATCH + b) * DI + d) * NST);
  float4 h0 = hi[0], h1 = hi[1], h2 = hi[2], h3 = hi[3];
  h[0]=h0.x; h[1]=h0.y; h[2]=h0.z; h[3]=h0.w; h[4]=h1.x; h[5]=h1.y; h[6]=h1.z; h[7]=h1.w;
  h[8]=h2.x; h[9]=h2.y; h[10]=h2.z; h[11]=h2.w; h[12]=h3.x; h[13]=h3.y; h[14]=h3.z; h[15]=h3.w;
  const u16* up = ub + (size_t)(b * SEQ + t0) * DI + d;
  const u16* gp = xpg + (size_t)(b * SEQ + t0) * NIG + DI + d;
  u16* yp = gy + (size_t)(b * SEQ + t0) * DI + d;
  for (int t = 0; t < LCH; ++t) {
    float uu = b2f(up[(size_t)t * DI]);
    float acc = 0.f;
    #pragma unroll
    for (int n = 0; n < NST; ++n) {
      h[n] = fmaf(h[n], dl[t * NST + n], bl[t * NST + n] * uu);
      acc = fmaf(h[n], cl[t * NST + n], acc);
    }
    float g = b2f(gp[(size_t)t * NIG]);
    yp[(size_t)t * DI] = f2b(siluf_(g) * acc);
  }
}

extern "C" void kernel_launch(void* const* d_in, const int* in_sizes, int n_in,
                              void* d_out, int out_size, void* d_ws, size_t ws_size,
                              hipStream_t stream) {
  const float* x      = (const float*)d_in[0];
  const float* ln_g   = (const float*)d_in[1];
  const float* ln_b   = (const float*)d_in[2];
  const float* W_in   = (const float*)d_in[3];
  const float* b_in   = (const float*)d_in[4];
  const float* conv_w = (const float*)d_in[5];
  const float* conv_b = (const float*)d_in[6];
  const float* W_A    = (const float*)d_in[7];
  const float* b_A    = (const float*)d_in[8];
  const float* W_B    = (const float*)d_in[9];
  const float* b_B    = (const float*)d_in[10];
  const float* W_C    = (const float*)d_in[11];
  const float* b_C    = (const float*)d_in[12];
  const float* W_dt   = (const float*)d_in[13];
  const float* b_dt   = (const float*)d_in[14];
  const float* W_S    = (const float*)d_in[15];
  const float* b_S    = (const float*)d_in[16];
  const float* W_gate = (const float*)d_in[17];
  const float* b_gate = (const float*)d_in[18];
  const float* W_out  = (const float*)d_in[19];
  const float* b_out  = (const float*)d_in[20];
  float* out = (float*)d_out;

  char* p = (char*)d_ws;
  auto alloc = [&](size_t bytes) { char* r = p; p += (bytes + 255) & ~(size_t)255; return r; };
  u16*   Wigb    = (u16*)alloc((size_t)NIG * DM * 2);   // [3072][768] = W_in | W_gate
  float* biasig  = (float*)alloc((size_t)NIG * 4);
  u16*   WSb     = (u16*)alloc((size_t)DI * DI * 2);    // first half of W_S only
  u16*   Woutb   = (u16*)alloc((size_t)DM * DI * 2);
  u16*   Wabcd   = (u16*)alloc((size_t)64 * DI * 2);
  float* bias64  = (float*)alloc(64 * 4);
  u16*   xnb     = (u16*)alloc((size_t)NTOK * DM * 2);
  u16*   xpg     = (u16*)alloc((size_t)NTOK * NIG * 2); // [tok][3072]: xp | gate (bf16)
  u16*   xab     = (u16*)alloc((size_t)NTOK * DI * 2);  // silu(conv) bf16; reused as gy
  u16*   ub      = (u16*)alloc((size_t)NTOK * DI * 2);  // u bf16
  float* decb    = (float*)alloc((size_t)NTOK * NST * 4);
  float* Bmb     = (float*)alloc((size_t)NTOK * NST * 4);
  float* Cmb     = (float*)alloc((size_t)NTOK * NST * 4);
  float* lend    = (float*)alloc((size_t)NCH * BATCH * DI * NST * 4);
  float* Hin     = (float*)alloc((size_t)NCH * BATCH * DI * NST * 4);
  float* P       = (float*)alloc((size_t)NCH * BATCH * NST * 4);
  u16* gy = xab;

  // weight prep
  cast_ingate<<<(NIG * DM + 255) / 256, 256, 0, stream>>>(W_in, W_gate, b_in, b_gate, Wigb, biasig);
  cast_bf16<<<(DI * DI / 4 + 255) / 256, 256, 0, stream>>>(W_S, WSb, DI * DI / 4);
  cast_bf16<<<(DM * DI / 4 + 255) / 256, 256, 0, stream>>>(W_out, Woutb, DM * DI / 4);
  cast_wabcd<<<(64 * DI + 255) / 256, 256, 0, stream>>>(W_A, W_dt, W_B, W_C, b_A, b_dt, b_B, b_C, Wabcd, bias64);

  ln_kernel<<<NTOK, 256, 0, stream>>>(x, ln_g, ln_b, xnb);

  // fused in|gate GEMM -> xpg bf16
  gemm_bt<2><<<dim3(NIG / 128, NTOK / 128), 512, 0, stream>>>(xnb, Wigb, biasig, nullptr, nullptr,
                                                              nullptr, xpg, NTOK, NIG, DM);

  conv_silu<<<NTOK * DI / 256, 256, 0, stream>>>(xpg, conv_w, conv_b, xab);

  // S GEMM with fused u = xa * sigmoid(Sp) -> ub bf16 (aux = xab, same buffer as A operand)
  gemm_bt<1><<<dim3(DI / 128, NTOK / 128), 512, 0, stream>>>(xab, WSb, b_S, nullptr, xab,
                                                             nullptr, ub, NTOK, DI, DI);

  gemm_abcd<<<NTOK / 64, 256, 0, stream>>>(ub, Wabcd, bias64, decb, Bmb, Cmb, NTOK, DI);

  scan_phase1<<<NCH * BATCH * (DI / 256), 256, 0, stream>>>(ub, decb, Bmb, lend, P);
  scan_phase2<<<BATCH * DI * NST / 256, 256, 0, stream>>>(lend, P, Hin);
  scan_phase3<<<NCH * BATCH * (DI / 256), 256, 0, stream>>>(ub, decb, Bmb, Cmb, Hin, xpg, gy);

  // out GEMM + residual (f32 out)
  gemm_bt<0><<<dim3(DM / 128, NTOK / 128), 512, 0, stream>>>(gy, Woutb, b_out, x, nullptr,
                                                             out, nullptr, NTOK, DM, DI);
}

// Round 8
// 205.961 us; speedup vs baseline: 2.2746x; 1.0943x over previous
//
#include <hip/hip_runtime.h>

// BayesianMambaBlock on MI355X (gfx950).
// LN -> fused (in|gate) GEMM (bf16 out) -> conv+silu (bf16) -> S GEMM (fused u, bf16 out) ->
// abcd GEMM split-K4 + combine (dec/B/C) -> chunked scan (phase3 fused gate) -> out GEMM (+resid, f32).
// gemm_bt: depth-3 software pipeline — 4 LDS buffers, counted s_waitcnt vmcnt(4) + raw s_barrier
// (never drain to 0 in main loop), chunk-XOR LDS swizzle, XCD-aware block swizzle.

typedef unsigned short u16;
using short8 = __attribute__((ext_vector_type(8))) short;
using f32x4  = __attribute__((ext_vector_type(4))) float;

#define BATCH 2
#define SEQ   2048
#define DM    768
#define DI    1536
#define NIG   (2*DI)        // fused in+gate width 3072
#define NST   16
#define LCH   64
#define NCH   32
#define NTOK  (BATCH*SEQ)   // 4096

__device__ __forceinline__ u16 f2b(float x) {
  unsigned u = __float_as_uint(x);
  u += 0x7FFFu + ((u >> 16) & 1u);   // round-to-nearest-even bf16
  return (u16)(u >> 16);
}
__device__ __forceinline__ float b2f(u16 v) { return __uint_as_float((unsigned)v << 16); }
__device__ __forceinline__ float sigmoidf_(float x) { return 1.f / (1.f + expf(-x)); }
__device__ __forceinline__ float siluf_(float x) { return x / (1.f + expf(-x)); }

// ---------------- f32 -> bf16 cast (vectorized) ----------------
__global__ __launch_bounds__(256) void cast_bf16(const float* __restrict__ in, u16* __restrict__ out, int n4) {
  int i = blockIdx.x * 256 + threadIdx.x;
  if (i >= n4) return;
  float4 v = ((const float4*)in)[i];
  ushort4 o; o.x = f2b(v.x); o.y = f2b(v.y); o.z = f2b(v.z); o.w = f2b(v.w);
  ((ushort4*)out)[i] = o;
}

// ---------------- concat W_in|W_gate -> bf16 [3072][768] + bias3072 ----------------
__global__ __launch_bounds__(256) void cast_ingate(const float* __restrict__ Wi, const float* __restrict__ Wg,
                                                   const float* __restrict__ bi, const float* __restrict__ bg,
                                                   u16* __restrict__ Wb, float* __restrict__ bias) {
  int i = blockIdx.x * 256 + threadIdx.x;   // < NIG*DM
  if (i >= NIG * DM) return;
  int r = i / DM, c = i % DM;
  Wb[i] = f2b(r < DI ? Wi[(size_t)r * DM + c] : Wg[(size_t)(r - DI) * DM + c]);
  if (i < NIG) bias[i] = (i < DI) ? bi[i] : bg[i - DI];
}

// ---------------- concat W_A/W_dt/W_B/W_C -> bf16 [64][DI] + bias64 ----------------
__global__ __launch_bounds__(256) void cast_wabcd(const float* __restrict__ WA, const float* __restrict__ Wdt,
                                                  const float* __restrict__ WB, const float* __restrict__ WC,
                                                  const float* __restrict__ bA, const float* __restrict__ bdt,
                                                  const float* __restrict__ bB, const float* __restrict__ bC,
                                                  u16* __restrict__ Wb, float* __restrict__ bias64) {
  int i = blockIdx.x * 256 + threadIdx.x;   // < 64*DI
  if (i >= 64 * DI) return;
  int r = i / DI, c = i % DI;
  const float* src = (r < 16) ? WA + (size_t)r * DI
                  : (r < 32) ? Wdt + (size_t)(r - 16) * DI
                  : (r < 48) ? WB + (size_t)(r - 32) * DI
                             : WC + (size_t)(r - 48) * DI;
  Wb[i] = f2b(src[c]);
  if (i < 64) bias64[i] = (i < 16) ? bA[i] : (i < 32) ? bdt[i - 16] : (i < 48) ? bB[i - 32] : bC[i - 48];
}

// ---------------- LayerNorm -> bf16 ----------------
__global__ __launch_bounds__(256) void ln_kernel(const float* __restrict__ x, const float* __restrict__ g,
                                                 const float* __restrict__ bb, u16* __restrict__ xn) {
  int m = blockIdx.x, tid = threadIdx.x;
  const float* xr = x + (size_t)m * DM;
  float v0 = xr[tid], v1 = xr[tid + 256], v2 = xr[tid + 512];
  float s  = v0 + v1 + v2;
  float s2 = fmaf(v0, v0, fmaf(v1, v1, v2 * v2));
  #pragma unroll
  for (int off = 32; off > 0; off >>= 1) { s += __shfl_down(s, off); s2 += __shfl_down(s2, off); }
  __shared__ float sh[8];
  int wave = tid >> 6, lane = tid & 63;
  if (lane == 0) { sh[wave] = s; sh[4 + wave] = s2; }
  __syncthreads();
  float S1 = sh[0] + sh[1] + sh[2] + sh[3];
  float S2 = sh[4] + sh[5] + sh[6] + sh[7];
  float mu = S1 * (1.f / DM);
  float var = S2 * (1.f / DM) - mu * mu;
  float rs = rsqrtf(var + 1e-5f);
  u16* o = xn + (size_t)m * DM;
  o[tid]       = f2b((v0 - mu) * rs * g[tid]       + bb[tid]);
  o[tid + 256] = f2b((v1 - mu) * rs * g[tid + 256] + bb[tid + 256]);
  o[tid + 512] = f2b((v2 - mu) * rs * g[tid + 512] + bb[tid + 512]);
}

// ---------------- bf16 MFMA NT-GEMM: acc = A[M][K] * B[N][K]^T + bias ----------------
// 512 threads, 8 waves, 128x128 block tile, 32x64 wave tile, BK=32.
// Depth-3 pipeline: 4 LDS buffers, counted vmcnt(4) + raw s_barrier; tail drains 4->2->0.
// MODE 0: C f32 = acc + bias + aux(resid, f32)
// MODE 1: u-mode: uv = b2f(auxb) * sigmoid(acc+bias); Cb = bf16(uv)
// MODE 2: Cb = bf16(acc + bias)
__device__ __forceinline__ void gll16(const void* g, void* l) {
  __builtin_amdgcn_global_load_lds((const __attribute__((address_space(1))) void*)g,
                                   (__attribute__((address_space(3))) void*)l, 16, 0, 0);
}

template <int MODE>
__global__ __launch_bounds__(512) void gemm_bt(const u16* __restrict__ A, const u16* __restrict__ B,
                                               const float* __restrict__ bias, const float* __restrict__ aux,
                                               const u16* __restrict__ auxb,
                                               float* __restrict__ C, u16* __restrict__ Cb,
                                               int M, int N, int K) {
  __shared__ __align__(16) u16 As[4][128 * 32];
  __shared__ __align__(16) u16 Bs[4][128 * 32];
  const int tid = threadIdx.x, wave = tid >> 6, lane = tid & 63;

  // XCD-aware bijective swizzle (nwg % 8 == 0 for all our grids)
  const int nbx = gridDim.x, nwg = nbx * gridDim.y;
  const int orig = blockIdx.y * nbx + blockIdx.x;
  const int cpx = nwg >> 3;
  const int swz = (orig & 7) * cpx + (orig >> 3);
  const int m0 = (swz / nbx) * 128, n0 = (swz % nbx) * 128;

  const int wm = (wave >> 1) * 32, wn = (wave & 1) * 64;
  const int fr = lane & 15, fq = lane >> 4;
  f32x4 acc[2][4] = {};

  // staging: LDS chunk c (linear dest) holds global k-chunk (c&3)^((c>>3)&3) of row c>>2
  const int c0 = tid;   // 512 chunks of 16B cover 128x32
  const u16* Ag0 = A + (size_t)(m0 + (c0 >> 2)) * K + ((c0 & 3) ^ ((c0 >> 3) & 3)) * 8;
  const u16* Bg0 = B + (size_t)(n0 + (c0 >> 2)) * K + ((c0 & 3) ^ ((c0 >> 3) & 3)) * 8;
  const int lofs = (wave * 64) * 8;   // wave-uniform LDS base; HW adds lane*16B

  // swizzled ds_read offsets (u16 units), 2-way max per 8 bank-slots
  int offA[2], offB[4];
  #pragma unroll
  for (int i = 0; i < 2; ++i) {
    int ra = wm + i * 16 + fr;
    offA[i] = ra * 32 + (fq ^ ((ra >> 1) & 3)) * 8;
  }
  #pragma unroll
  for (int i = 0; i < 4; ++i) {
    int rb = wn + i * 16 + fr;
    offB[i] = rb * 32 + (fq ^ ((rb >> 1) & 3)) * 8;
  }

  const int nk = K >> 5;   // >= 24 for all our GEMMs

#define STAGE_BT(tt) { gll16(Ag0 + (tt) * 32, (u16*)As[(tt) & 3] + lofs); \
                       gll16(Bg0 + (tt) * 32, (u16*)Bs[(tt) & 3] + lofs); }
#define COMPUTE_BT(tt) { const u16* as_ = As[(tt) & 3]; const u16* bs_ = Bs[(tt) & 3]; \
    short8 av[2], bv[4]; \
    _Pragma("unroll") for (int i = 0; i < 2; ++i) av[i] = *(const short8*)(as_ + offA[i]); \
    _Pragma("unroll") for (int i = 0; i < 4; ++i) bv[i] = *(const short8*)(bs_ + offB[i]); \
    _Pragma("unroll") for (int mi = 0; mi < 2; ++mi) \
      _Pragma("unroll") for (int ni = 0; ni < 4; ++ni) \
        acc[mi][ni] = __builtin_amdgcn_mfma_f32_16x16x32_bf16(av[mi], bv[ni], acc[mi][ni], 0, 0, 0); }

  STAGE_BT(0); STAGE_BT(1); STAGE_BT(2);   // 6 loads in flight per wave

  for (int t = 0; t < nk - 3; ++t) {
    asm volatile("s_waitcnt vmcnt(4)" ::: "memory");   // tile t arrived; t+1,t+2 still in flight
    __builtin_amdgcn_s_barrier();
    STAGE_BT(t + 3);                                   // overwrites buf read at t-1 (all done)
    COMPUTE_BT(t);
  }
  asm volatile("s_waitcnt vmcnt(4)" ::: "memory");
  __builtin_amdgcn_s_barrier();
  COMPUTE_BT(nk - 3);
  asm volatile("s_waitcnt vmcnt(2)" ::: "memory");
  __builtin_amdgcn_s_barrier();
  COMPUTE_BT(nk - 2);
  asm volatile("s_waitcnt vmcnt(0)" ::: "memory");
  __builtin_amdgcn_s_barrier();
  COMPUTE_BT(nk - 1);
#undef STAGE_BT
#undef COMPUTE_BT

  #pragma unroll
  for (int ni = 0; ni < 4; ++ni) {
    int col = n0 + wn + ni * 16 + fr;
    float bv_ = bias[col];
    #pragma unroll
    for (int mi = 0; mi < 2; ++mi) {
      int row = m0 + wm + mi * 16 + fq * 4;
      #pragma unroll
      for (int j = 0; j < 4; ++j) {
        size_t off = (size_t)(row + j) * N + col;
        float z = acc[mi][ni][j] + bv_;
        if (MODE == 0) {
          C[off] = z + aux[off];
        } else if (MODE == 1) {
          Cb[off] = f2b(b2f(auxb[off]) * sigmoidf_(z));
        } else {
          Cb[off] = f2b(z);
        }
      }
    }
  }
}

// ---------------- abcd GEMM split-K: Zp[ks] = ub[M][Kq] * Wabcd[64][Kq]^T ----------------
// grid (M/64, 4); 256 threads, 64x64 tile, BK=64, double-buffered (__syncthreads).
__global__ __launch_bounds__(256) void gemm_abcd(const u16* __restrict__ A, const u16* __restrict__ B,
                                                 float* __restrict__ Zp, int M, int K) {
  __shared__ __align__(16) u16 As[2][64 * 64];
  __shared__ __align__(16) u16 Bs[2][64 * 64];
  const int tid = threadIdx.x, wave = tid >> 6, lane = tid & 63;
  const int m0 = blockIdx.x * 64;
  const int ks = blockIdx.y;
  const int Kq = K >> 2;            // 384
  const int kbase = ks * Kq;
  const int wm = wave * 16;
  const int fr = lane & 15, fq = lane >> 4;
  f32x4 acc[4] = {};

  // 512 chunks of 16B cover 64x64; chunk c: row=c>>3, LDS slot c&7 holds k-chunk (c&7)^(row&7)
  const int c0 = tid, c1 = tid + 256;
  const u16* Ag0 = A + (size_t)(m0 + (c0 >> 3)) * K + kbase + ((c0 & 7) ^ ((c0 >> 3) & 7)) * 8;
  const u16* Ag1 = A + (size_t)(m0 + (c1 >> 3)) * K + kbase + ((c1 & 7) ^ ((c1 >> 3) & 7)) * 8;
  const u16* Bg0 = B + (size_t)(c0 >> 3) * K + kbase + ((c0 & 7) ^ ((c0 >> 3) & 7)) * 8;
  const u16* Bg1 = B + (size_t)(c1 >> 3) * K + kbase + ((c1 & 7) ^ ((c1 >> 3) & 7)) * 8;
  const int lo0 = (wave * 64) * 8;
  const int lo1 = (256 + wave * 64) * 8;

  int offAv[2], offBv[2][4];
  {
    int r = wm + fr;
    #pragma unroll
    for (int kk = 0; kk < 2; ++kk) offAv[kk] = r * 64 + ((kk * 4 + fq) ^ (r & 7)) * 8;
    #pragma unroll
    for (int i = 0; i < 4; ++i) {
      int rb = i * 16 + fr;
      #pragma unroll
      for (int kk = 0; kk < 2; ++kk) offBv[kk][i] = rb * 64 + ((kk * 4 + fq) ^ (rb & 7)) * 8;
    }
  }

  const int nk = Kq >> 6;   // 6
  gll16(Ag0, (u16*)As[0] + lo0);
  gll16(Ag1, (u16*)As[0] + lo1);
  gll16(Bg0, (u16*)Bs[0] + lo0);
  gll16(Bg1, (u16*)Bs[0] + lo1);

  for (int t = 0; t < nk; ++t) {
    __syncthreads();
    if (t + 1 < nk) {
      int ko = (t + 1) * 64;
      gll16(Ag0 + ko, (u16*)As[(t + 1) & 1] + lo0);
      gll16(Ag1 + ko, (u16*)As[(t + 1) & 1] + lo1);
      gll16(Bg0 + ko, (u16*)Bs[(t + 1) & 1] + lo0);
      gll16(Bg1 + ko, (u16*)Bs[(t + 1) & 1] + lo1);
    }
    const u16* as = As[t & 1];
    const u16* bs = Bs[t & 1];
    #pragma unroll
    for (int kk = 0; kk < 2; ++kk) {
      short8 av = *(const short8*)(as + offAv[kk]);
      short8 bv[4];
      #pragma unroll
      for (int i = 0; i < 4; ++i) bv[i] = *(const short8*)(bs + offBv[kk][i]);
      #pragma unroll
      for (int ni = 0; ni < 4; ++ni)
        acc[ni] = __builtin_amdgcn_mfma_f32_16x16x32_bf16(av, bv[ni], acc[ni], 0, 0, 0);
    }
  }

  float* zp = Zp + (size_t)ks * M * 64;
  #pragma unroll
  for (int ni = 0; ni < 4; ++ni) {
    int col = ni * 16 + fr;
    #pragma unroll
    for (int j = 0; j < 4; ++j) {
      int row = m0 + wm + fq * 4 + j;
      zp[(size_t)row * 64 + col] = acc[ni][j];
    }
  }
}

// combine split-K partials; fused dec/Bm/Cm epilogue
__global__ __launch_bounds__(256) void abcd_combine(const float* __restrict__ Zp, const float* __restrict__ bias64,
                                                    float* __restrict__ dec, float* __restrict__ Bm,
                                                    float* __restrict__ Cm, int M) {
  int idx = blockIdx.x * 256 + threadIdx.x;  // < M*16
  int row = idx >> 4, n = idx & 15;
  float zA = bias64[n], zDt = bias64[16 + n], zB = bias64[32 + n], zC = bias64[48 + n];
  #pragma unroll
  for (int ks = 0; ks < 4; ++ks) {
    const float* zp = Zp + ((size_t)ks * M + row) * 64;
    zA += zp[n]; zDt += zp[16 + n]; zB += zp[32 + n]; zC += zp[48 + n];
  }
  size_t o = (size_t)row * NST + n;
  dec[o] = expf(-expf(zA + zDt));
  Bm[o] = zB;
  Cm[o] = zC;
}

// ---------------- depthwise causal conv (k=4) + bias + silu; short8-vectorized ----------------
__global__ __launch_bounds__(256) void conv_silu(const u16* __restrict__ xpg, const float* __restrict__ cw,
                                                 const float* __restrict__ cb, u16* __restrict__ xab) {
  int idx = blockIdx.x * 256 + threadIdx.x;   // < NTOK*DI/8
  int d8 = idx % (DI / 8);
  int token = idx / (DI / 8);
  int t = token % SEQ;
  int d0 = d8 * 8;
  const short8* xv = (const short8*)(xpg + (size_t)token * NIG + d0);
  short8 z8 = {0, 0, 0, 0, 0, 0, 0, 0};
  short8 x3 = (t >= 3) ? xv[-3 * (NIG / 8)] : z8;
  short8 x2 = (t >= 2) ? xv[-2 * (NIG / 8)] : z8;
  short8 x1 = (t >= 1) ? xv[-1 * (NIG / 8)] : z8;
  short8 x0 = xv[0];
  const float4* cw4 = (const float4*)cw;
  float4 cbl = ((const float4*)cb)[d8 * 2], cbh = ((const float4*)cb)[d8 * 2 + 1];
  float cbv[8] = {cbl.x, cbl.y, cbl.z, cbl.w, cbh.x, cbh.y, cbh.z, cbh.w};
  short8 o;
  #pragma unroll
  for (int j = 0; j < 8; ++j) {
    float4 w = cw4[d0 + j];
    float a = cbv[j];
    a = fmaf(b2f((u16)x3[j]), w.x, a);
    a = fmaf(b2f((u16)x2[j]), w.y, a);
    a = fmaf(b2f((u16)x1[j]), w.z, a);
    a = fmaf(b2f((u16)x0[j]), w.w, a);
    o[j] = (short)f2b(siluf_(a));
  }
  *(short8*)(xab + (size_t)token * DI + d0) = o;
}

// ---------------- chunked selective scan ----------------
// phase1: per-chunk local scan from h=0 -> lend[c][b][d][16]; P[c][b][16]=prod(dec)
__global__ __launch_bounds__(256) void scan_phase1(const u16* __restrict__ ub, const float* __restrict__ dec,
                                                   const float* __restrict__ Bm, float* __restrict__ lend,
                                                   float* __restrict__ P) {
  __shared__ float dl[LCH * NST], bl[LCH * NST];
  int bid = blockIdx.x;
  int dblk = bid % 6, b = (bid / 6) % BATCH, c = bid / (6 * BATCH);
  int d = dblk * 256 + threadIdx.x;
  int t0 = c * LCH;
  size_t base16 = (size_t)(b * SEQ + t0) * NST;
  for (int i = threadIdx.x; i < LCH * NST; i += 256) { dl[i] = dec[base16 + i]; bl[i] = Bm[base16 + i]; }
  __syncthreads();
  float h[NST];
  #pragma unroll
  for (int n = 0; n < NST; ++n) h[n] = 0.f;
  const u16* up = ub + (size_t)(b * SEQ + t0) * DI + d;
  for (int t = 0; t < LCH; ++t) {
    float uu = b2f(up[(size_t)t * DI]);
    #pragma unroll
    for (int n = 0; n < NST; ++n) h[n] = fmaf(h[n], dl[t * NST + n], bl[t * NST + n] * uu);
  }
  float* lo = lend + ((size_t)(c * BATCH + b) * DI + d) * NST;
  ((float4*)lo)[0] = make_float4(h[0], h[1], h[2], h[3]);
  ((float4*)lo)[1] = make_float4(h[4], h[5], h[6], h[7]);
  ((float4*)lo)[2] = make_float4(h[8], h[9], h[10], h[11]);
  ((float4*)lo)[3] = make_float4(h[12], h[13], h[14], h[15]);
  if (dblk == 0 && threadIdx.x < NST) {
    float pr = 1.f;
    for (int t = 0; t < LCH; ++t) pr *= dl[t * NST + threadIdx.x];
    P[(size_t)(c * BATCH + b) * NST + threadIdx.x] = pr;
  }
}

// phase2: cross-chunk scan, parallel over (b,d,n); Hin[c] = state entering chunk c
__global__ __launch_bounds__(256) void scan_phase2(const float* __restrict__ lend, const float* __restrict__ P,
                                                   float* __restrict__ Hin) {
  int flat = blockIdx.x * 256 + threadIdx.x;  // < BATCH*DI*NST
  int n = flat & 15;
  int d = (flat >> 4) % DI;
  int b = flat / (DI * NST);
  float h = 0.f;
  for (int c = 0; c < NCH; ++c) {
    size_t idx = ((size_t)(c * BATCH + b) * DI + d) * NST + n;
    Hin[idx] = h;
    h = fmaf(P[(size_t)(c * BATCH + b) * NST + n], h, lend[idx]);
  }
}

// phase3: replay chunk from Hin, emit gy = bf16(silu(gate) * y); gate is cols DI..2DI of xpg
__global__ __launch_bounds__(256) void scan_phase3(const u16* __restrict__ ub, const float* __restrict__ dec,
                                                   const float* __restrict__ Bm, const float* __restrict__ Cm,
                                                   const float* __restrict__ Hin, const u16* __restrict__ xpg,
                                                   u16* __restrict__ gy) {
  __shared__ float dl[LCH * NST], bl[LCH * NST], cl[LCH * NST];
  int bid = blockIdx.x;
  int dblk = bid % 6, b = (bid / 6) % BATCH, c = bid / (6 * BATCH);
  int d = dblk * 256 + threadIdx.x;
  int t0 = c * LCH;
  size_t base16 = (size_t)(b * SEQ + t0) * NST;
  for (int i = threadIdx.x; i < LCH * NST; i += 256) {
    dl[i] = dec[base16 + i]; bl[i] = Bm[base16 + i]; cl[i] = Cm[base16 + i];
  }
  __syncthreads();
  float h[NST];
  const float4* hi = (const float4*)(Hin + ((size_t)(c * BATCH + b) * DI + d) * NST);
  float4 h0 = hi[0], h1 = hi[1], h2 = hi[2], h3 = hi[3];
  h[0]=h0.x; h[1]=h0.y; h[2]=h0.z; h[3]=h0.w; h[4]=h1.x; h[5]=h1.y; h[6]=h1.z; h[7]=h1.w;
  h[8]=h2.x; h[9]=h2.y; h[10]=h2.z; h[11]=h2.w; h[12]=h3.x; h[13]=h3.y; h[14]=h3.z; h[15]=h3.w;
  const u16* up = ub + (size_t)(b * SEQ + t0) * DI + d;
  const u16* gp = xpg + (size_t)(b * SEQ + t0) * NIG + DI + d;
  u16* yp = gy + (size_t)(b * SEQ + t0) * DI + d;
  for (int t = 0; t < LCH; ++t) {
    float uu = b2f(up[(size_t)t * DI]);
    float acc = 0.f;
    #pragma unroll
    for (int n = 0; n < NST; ++n) {
      h[n] = fmaf(h[n], dl[t * NST + n], bl[t * NST + n] * uu);
      acc = fmaf(h[n], cl[t * NST + n], acc);
    }
    float g = b2f(gp[(size_t)t * NIG]);
    yp[(size_t)t * DI] = f2b(siluf_(g) * acc);
  }
}

extern "C" void kernel_launch(void* const* d_in, const int* in_sizes, int n_in,
                              void* d_out, int out_size, void* d_ws, size_t ws_size,
                              hipStream_t stream) {
  const float* x      = (const float*)d_in[0];
  const float* ln_g   = (const float*)d_in[1];
  const float* ln_b   = (const float*)d_in[2];
  const float* W_in   = (const float*)d_in[3];
  const float* b_in   = (const float*)d_in[4];
  const float* conv_w = (const float*)d_in[5];
  const float* conv_b = (const float*)d_in[6];
  const float* W_A    = (const float*)d_in[7];
  const float* b_A    = (const float*)d_in[8];
  const float* W_B    = (const float*)d_in[9];
  const float* b_B    = (const float*)d_in[10];
  const float* W_C    = (const float*)d_in[11];
  const float* b_C    = (const float*)d_in[12];
  const float* W_dt   = (const float*)d_in[13];
  const float* b_dt   = (const float*)d_in[14];
  const float* W_S    = (const float*)d_in[15];
  const float* b_S    = (const float*)d_in[16];
  const float* W_gate = (const float*)d_in[17];
  const float* b_gate = (const float*)d_in[18];
  const float* W_out  = (const float*)d_in[19];
  const float* b_out  = (const float*)d_in[20];
  float* out = (float*)d_out;

  char* p = (char*)d_ws;
  auto alloc = [&](size_t bytes) { char* r = p; p += (bytes + 255) & ~(size_t)255; return r; };
  u16*   Wigb    = (u16*)alloc((size_t)NIG * DM * 2);   // [3072][768] = W_in | W_gate
  float* biasig  = (float*)alloc((size_t)NIG * 4);
  u16*   WSb     = (u16*)alloc((size_t)DI * DI * 2);    // first half of W_S only
  u16*   Woutb   = (u16*)alloc((size_t)DM * DI * 2);
  u16*   Wabcd   = (u16*)alloc((size_t)64 * DI * 2);
  float* bias64  = (float*)alloc(64 * 4);
  u16*   xnb     = (u16*)alloc((size_t)NTOK * DM * 2);
  u16*   xpg     = (u16*)alloc((size_t)NTOK * NIG * 2); // [tok][3072]: xp | gate (bf16)
  u16*   xab     = (u16*)alloc((size_t)NTOK * DI * 2);  // silu(conv) bf16; reused as gy
  u16*   ub      = (u16*)alloc((size_t)NTOK * DI * 2);  // u bf16
  float* Zp      = (float*)alloc((size_t)4 * NTOK * 64 * 4);  // split-K partials
  float* decb    = (float*)alloc((size_t)NTOK * NST * 4);
  float* Bmb     = (float*)alloc((size_t)NTOK * NST * 4);
  float* Cmb     = (float*)alloc((size_t)NTOK * NST * 4);
  float* lend    = (float*)alloc((size_t)NCH * BATCH * DI * NST * 4);
  float* Hin     = (float*)alloc((size_t)NCH * BATCH * DI * NST * 4);
  float* P       = (float*)alloc((size_t)NCH * BATCH * NST * 4);
  u16* gy = xab;

  // weight prep
  cast_ingate<<<(NIG * DM + 255) / 256, 256, 0, stream>>>(W_in, W_gate, b_in, b_gate, Wigb, biasig);
  cast_bf16<<<(DI * DI / 4 + 255) / 256, 256, 0, stream>>>(W_S, WSb, DI * DI / 4);
  cast_bf16<<<(DM * DI / 4 + 255) / 256, 256, 0, stream>>>(W_out, Woutb, DM * DI / 4);
  cast_wabcd<<<(64 * DI + 255) / 256, 256, 0, stream>>>(W_A, W_dt, W_B, W_C, b_A, b_dt, b_B, b_C, Wabcd, bias64);

  ln_kernel<<<NTOK, 256, 0, stream>>>(x, ln_g, ln_b, xnb);

  // fused in|gate GEMM -> xpg bf16
  gemm_bt<2><<<dim3(NIG / 128, NTOK / 128), 512, 0, stream>>>(xnb, Wigb, biasig, nullptr, nullptr,
                                                              nullptr, xpg, NTOK, NIG, DM);

  conv_silu<<<NTOK * (DI / 8) / 256, 256, 0, stream>>>(xpg, conv_w, conv_b, xab);

  // S GEMM with fused u = xa * sigmoid(Sp) -> ub bf16 (aux = xab, same buffer as A operand)
  gemm_bt<1><<<dim3(DI / 128, NTOK / 128), 512, 0, stream>>>(xab, WSb, b_S, nullptr, xab,
                                                             nullptr, ub, NTOK, DI, DI);

  gemm_abcd<<<dim3(NTOK / 64, 4), 256, 0, stream>>>(ub, Wabcd, Zp, NTOK, DI);
  abcd_combine<<<NTOK * 16 / 256, 256, 0, stream>>>(Zp, bias64, decb, Bmb, Cmb, NTOK);

  scan_phase1<<<NCH * BATCH * (DI / 256), 256, 0, stream>>>(ub, decb, Bmb, lend, P);
  scan_phase2<<<BATCH * DI * NST / 256, 256, 0, stream>>>(lend, P, Hin);
  scan_phase3<<<NCH * BATCH * (DI / 256), 256, 0, stream>>>(ub, decb, Bmb, Cmb, Hin, xpg, gy);

  // out GEMM + residual (f32 out)
  gemm_bt<0><<<dim3(DM / 128, NTOK / 128), 512, 0, stream>>>(gy, Woutb, b_out, x, nullptr,
                                                             out, nullptr, NTOK, DM, DI);
}